// Round 1
// baseline (1965.146 us; speedup 1.0000x reference)
//
#include <hip/hip_runtime.h>
#include <hip/hip_bf16.h>
#include <math.h>

#define N_NODES 4096
#define N_EDGES 16384
#define CLIPD   512
#define HID     1024
#define NH      4
#define OUTD    2048
#define NB      32

static __device__ __forceinline__ float lrelu(float x) { return x >= 0.f ? x : 0.2f * x; }

// ---------------------------------------------------------------------------
// v[k][h] = sum_c We[k][h*C+c] * ae[h*C+c]   (folds edge-attr projection into
// a single 512x4 matrix; avoids materializing e = edge_attr @ We entirely)
// ---------------------------------------------------------------------------
template<int C>
__global__ __launch_bounds__(256) void v_kernel(const float* __restrict__ We,
                                                const float* __restrict__ ae,
                                                float* __restrict__ v) {
  const int k = blockIdx.x;           // 0..CLIPD-1
  const int tid = threadIdx.x;
  const float* row = We + (size_t)k * (NH * C);
  float acc[NH] = {0.f, 0.f, 0.f, 0.f};
  for (int c = tid; c < C; c += 256) {
    for (int h = 0; h < NH; ++h) acc[h] += row[h * C + c] * ae[h * C + c];
  }
  for (int h = 0; h < NH; ++h)
    for (int o = 32; o > 0; o >>= 1) acc[h] += __shfl_down(acc[h], o);
  __shared__ float red[4][NH];
  const int wid = tid >> 6, lane = tid & 63;
  if (lane == 0)
    for (int h = 0; h < NH; ++h) red[wid][h] = acc[h];
  __syncthreads();
  if (tid < NH) v[k * NH + tid] = red[0][tid] + red[1][tid] + red[2][tid] + red[3][tid];
}

// ---------------------------------------------------------------------------
// CSR build: degree count, 1-block scan, slot fill
// ---------------------------------------------------------------------------
__global__ void deg_kernel(const int* __restrict__ ei, int* __restrict__ deg) {
  int e = blockIdx.x * 256 + threadIdx.x;
  if (e < N_EDGES) atomicAdd(&deg[ei[N_EDGES + e]], 1);
}

__global__ __launch_bounds__(1024) void scan_kernel(const int* __restrict__ deg, int* __restrict__ offs) {
  __shared__ int s[1024];
  const int t = threadIdx.x;
  int d0 = deg[4 * t], d1 = deg[4 * t + 1], d2 = deg[4 * t + 2], d3 = deg[4 * t + 3];
  s[t] = d0 + d1 + d2 + d3;
  __syncthreads();
  for (int off = 1; off < 1024; off <<= 1) {
    int v = (t >= off) ? s[t - off] : 0;
    __syncthreads();
    s[t] += v;
    __syncthreads();
  }
  int base = (t > 0) ? s[t - 1] : 0;
  offs[4 * t] = base;
  offs[4 * t + 1] = base + d0;
  offs[4 * t + 2] = base + d0 + d1;
  offs[4 * t + 3] = base + d0 + d1 + d2;
  if (t == 1023) offs[4096] = s[1023];
}

__global__ void fill_kernel(const int* __restrict__ ei, const int* __restrict__ offs,
                            int* __restrict__ cursor, int* __restrict__ csr_src,
                            int* __restrict__ csr_eid) {
  int e = blockIdx.x * 256 + threadIdx.x;
  if (e >= N_EDGES) return;
  int dst = ei[N_EDGES + e];
  int pos = offs[dst] + atomicAdd(&cursor[dst], 1);
  csr_src[pos] = ei[e];
  csr_eid[pos] = e;
}

// ---------------------------------------------------------------------------
// a_e for both layers in one pass over edge_attr (read 32 MB once), plus
// segment-sum into ae_sum (for the self-loop 'mean' edge attr, applied to v)
// ---------------------------------------------------------------------------
__global__ __launch_bounds__(256) void ae_kernel(const float* __restrict__ ea, const int* __restrict__ ei,
                                                 const float* __restrict__ v1, const float* __restrict__ v2,
                                                 float* __restrict__ ae1, float* __restrict__ ae2,
                                                 float* __restrict__ aesum1, float* __restrict__ aesum2) {
  __shared__ float4 v1s[CLIPD];
  __shared__ float4 v2s[CLIPD];
  const int tid = threadIdx.x;
  v1s[tid] = ((const float4*)v1)[tid];
  v1s[tid + 256] = ((const float4*)v1)[tid + 256];
  v2s[tid] = ((const float4*)v2)[tid];
  v2s[tid + 256] = ((const float4*)v2)[tid + 256];
  __syncthreads();
  const int wid = tid >> 6, lane = tid & 63;
  for (int i = 0; i < 16; ++i) {
    const int e = blockIdx.x * 64 + wid * 16 + i;
    const float* row = ea + (size_t)e * CLIPD;
    float a1[NH] = {0.f, 0.f, 0.f, 0.f}, a2[NH] = {0.f, 0.f, 0.f, 0.f};
    for (int k = lane; k < CLIPD; k += 64) {
      float x = row[k];
      float4 w1 = v1s[k];
      float4 w2 = v2s[k];
      a1[0] += x * w1.x; a1[1] += x * w1.y; a1[2] += x * w1.z; a1[3] += x * w1.w;
      a2[0] += x * w2.x; a2[1] += x * w2.y; a2[2] += x * w2.z; a2[3] += x * w2.w;
    }
    for (int h = 0; h < NH; ++h)
      for (int o = 32; o > 0; o >>= 1) {
        a1[h] += __shfl_down(a1[h], o);
        a2[h] += __shfl_down(a2[h], o);
      }
    if (lane == 0) {
      int dst = ei[N_EDGES + e];
      for (int h = 0; h < NH; ++h) {
        ae1[e * NH + h] = a1[h];
        ae2[e * NH + h] = a2[h];
        atomicAdd(&aesum1[dst * NH + h], a1[h]);
        atomicAdd(&aesum2[dst * NH + h], a2[h]);
      }
    }
  }
}

__global__ void loopdiv_kernel(float* __restrict__ s1, float* __restrict__ s2,
                               const int* __restrict__ deg) {
  int i = blockIdx.x * 256 + threadIdx.x;
  if (i >= N_NODES * NH) return;
  float c = fmaxf((float)deg[i >> 2], 1.0f);
  s1[i] /= c;
  s2[i] /= c;
}

// ---------------------------------------------------------------------------
// Plain fp32 tiled GEMM, C = A@B, 64x64 tile, BK=16, 4x4 per thread.
// EPI=1: C = prelu(A@B + bias, *pa)
// ---------------------------------------------------------------------------
template<int EPI>
__global__ __launch_bounds__(256) void gemm_kernel(const float* __restrict__ A, const float* __restrict__ B,
                                                   float* __restrict__ C, const int M, const int Nn, const int K,
                                                   const float* __restrict__ bias, const float* __restrict__ pa) {
  __shared__ float As[16][68];
  __shared__ float Bs[16][68];
  const int tid = threadIdx.x;
  const int tx = tid & 15, ty = tid >> 4;
  const int brow = blockIdx.y * 64, bcol = blockIdx.x * 64;
  float acc[4][4] = {};
  for (int kt = 0; kt < K; kt += 16) {
#pragma unroll
    for (int it = 0; it < 4; ++it) {
      int l = tid + it * 256;
      int ar = l >> 4, ak = l & 15;
      As[ak][ar] = A[(size_t)(brow + ar) * K + kt + ak];
      int bc = l & 63, bk = l >> 6;
      Bs[bk][bc] = B[(size_t)(kt + bk) * Nn + bcol + bc];
    }
    __syncthreads();
#pragma unroll
    for (int kk = 0; kk < 16; ++kk) {
      float4 a4 = *(const float4*)&As[kk][ty * 4];
      float4 b4 = *(const float4*)&Bs[kk][tx * 4];
      float av[4] = {a4.x, a4.y, a4.z, a4.w};
      float bv[4] = {b4.x, b4.y, b4.z, b4.w};
#pragma unroll
      for (int i = 0; i < 4; ++i)
#pragma unroll
        for (int j = 0; j < 4; ++j) acc[i][j] += av[i] * bv[j];
    }
    __syncthreads();
  }
  const int prow = brow + ty * 4, pcol = bcol + tx * 4;
  float ap = 0.f;
  if (EPI) ap = *pa;
#pragma unroll
  for (int i = 0; i < 4; ++i) {
    float4 o;
    float* op = &o.x;
#pragma unroll
    for (int j = 0; j < 4; ++j) {
      float v = acc[i][j];
      if (EPI) {
        v += bias[pcol + j];
        v = v >= 0.f ? v : ap * v;
      }
      op[j] = v;
    }
    *(float4*)&C[(size_t)(prow + i) * Nn + pcol] = o;
  }
}

// ---------------------------------------------------------------------------
// Per-node attention dots a_s, a_d  (h[n,h,:] . asrc[h,:], . adst[h,:])
// ---------------------------------------------------------------------------
template<int C>
__global__ __launch_bounds__(256) void nodedot_kernel(const float* __restrict__ hbuf,
                                                      const float* __restrict__ asrc,
                                                      const float* __restrict__ adst,
                                                      float* __restrict__ as_, float* __restrict__ ad_) {
  const int n = blockIdx.x, tid = threadIdx.x;
  const float* row = hbuf + (size_t)n * (NH * C);
  float s[NH] = {0.f, 0.f, 0.f, 0.f}, d[NH] = {0.f, 0.f, 0.f, 0.f};
  for (int c = tid; c < C; c += 256) {
    for (int h = 0; h < NH; ++h) {
      float hv = row[h * C + c];
      s[h] += hv * asrc[h * C + c];
      d[h] += hv * adst[h * C + c];
    }
  }
  for (int h = 0; h < NH; ++h)
    for (int o = 32; o > 0; o >>= 1) {
      s[h] += __shfl_down(s[h], o);
      d[h] += __shfl_down(d[h], o);
    }
  __shared__ float rs[4][NH], rd[4][NH];
  const int wid = tid >> 6, lane = tid & 63;
  if (lane == 0)
    for (int h = 0; h < NH; ++h) {
      rs[wid][h] = s[h];
      rd[wid][h] = d[h];
    }
  __syncthreads();
  if (tid < NH)
    as_[n * NH + tid] = rs[0][tid] + rs[1][tid] + rs[2][tid] + rs[3][tid];
  else if (tid < 2 * NH) {
    int h = tid - NH;
    ad_[n * NH + h] = rd[0][h] + rd[1][h] + rd[2][h] + rd[3][h];
  }
}

// ---------------------------------------------------------------------------
// Per-node softmax + aggregation (+ self loop), mean over heads + bias + prelu
// ---------------------------------------------------------------------------
template<int C>
__global__ __launch_bounds__(256) void agg_kernel(const float* __restrict__ hbuf,
                                                  const float* __restrict__ as_, const float* __restrict__ ad_,
                                                  const float* __restrict__ aee, const float* __restrict__ aeloop,
                                                  const int* __restrict__ offs, const int* __restrict__ csr_src,
                                                  const int* __restrict__ csr_eid,
                                                  const float* __restrict__ bias, const float* __restrict__ pa,
                                                  float* __restrict__ out) {
  constexpr int HC = NH * C;
  constexpr int CT = C / 256;
  const int n = blockIdx.x;
  const int tid = threadIdx.x;
  const int off = offs[n];
  const int deg = offs[n + 1] - off;
  __shared__ float minv[NH], dinv[NH], wself[NH];
  __shared__ float wch[32][NH];
  __shared__ int sch[32];
  if (tid < NH) {
    const int h = tid;
    const float adn = ad_[n * NH + h];
    const float aself = lrelu(as_[n * NH + h] + adn + aeloop[n * NH + h]);
    float m = aself;
    for (int i = 0; i < deg; ++i) {
      float a = lrelu(as_[csr_src[off + i] * NH + h] + adn + aee[csr_eid[off + i] * NH + h]);
      m = fmaxf(m, a);
    }
    float den = __expf(aself - m);
    for (int i = 0; i < deg; ++i) {
      float a = lrelu(as_[csr_src[off + i] * NH + h] + adn + aee[csr_eid[off + i] * NH + h]);
      den += __expf(a - m);
    }
    minv[h] = m;
    dinv[h] = 1.0f / den;
    wself[h] = __expf(aself - m) / den;
  }
  __syncthreads();
  float acc[NH][CT];
  for (int h = 0; h < NH; ++h)
    for (int c = 0; c < CT; ++c) acc[h][c] = 0.f;
  for (int base = 0; base < deg; base += 32) {
    const int cnt = min(32, deg - base);
    if (tid < cnt * NH) {
      const int i = tid >> 2, h = tid & 3;
      const int sidx = csr_src[off + base + i];
      float a = lrelu(as_[sidx * NH + h] + ad_[n * NH + h] + aee[csr_eid[off + base + i] * NH + h]);
      wch[i][h] = __expf(a - minv[h]) * dinv[h];
      if (h == 0) sch[i] = sidx;
    }
    __syncthreads();
    for (int i = 0; i < cnt; ++i) {
      const float* hp = hbuf + (size_t)sch[i] * HC + tid;
#pragma unroll
      for (int h = 0; h < NH; ++h) {
        const float w = wch[i][h];
#pragma unroll
        for (int c = 0; c < CT; ++c) acc[h][c] += w * hp[h * C + c * 256];
      }
    }
    __syncthreads();
  }
  {
    const float* hp = hbuf + (size_t)n * HC + tid;
#pragma unroll
    for (int h = 0; h < NH; ++h) {
      const float w = wself[h];
#pragma unroll
      for (int c = 0; c < CT; ++c) acc[h][c] += w * hp[h * C + c * 256];
    }
  }
  const float ap = *pa;
#pragma unroll
  for (int c = 0; c < CT; ++c) {
    const int col = tid + c * 256;
    float v = 0.25f * (acc[0][c] + acc[1][c] + acc[2][c] + acc[3][c]) + bias[col];
    out[(size_t)n * C + col] = v >= 0.f ? v : ap * v;
  }
}

// ---------------------------------------------------------------------------
// gate = gh2 @ gW3 + gb3   (matvec)
// ---------------------------------------------------------------------------
__global__ __launch_bounds__(256) void gate3_kernel(const float* __restrict__ gh2, const float* __restrict__ gW3,
                                                    const float* __restrict__ gb3, float* __restrict__ gate) {
  const int n = blockIdx.x, tid = threadIdx.x;
  const float* row = gh2 + (size_t)n * HID;
  float acc = 0.f;
  for (int c = tid; c < HID; c += 256) acc += row[c] * gW3[c];
  for (int o = 32; o > 0; o >>= 1) acc += __shfl_down(acc, o);
  __shared__ float red[4];
  const int wid = tid >> 6, lane = tid & 63;
  if (lane == 0) red[wid] = acc;
  __syncthreads();
  if (tid == 0) gate[n] = red[0] + red[1] + red[2] + red[3] + gb3[0];
}

// batch is sorted -> contiguous graph ranges
__global__ void gstart_kernel(const int* __restrict__ batch, int* __restrict__ gstart) {
  int n = blockIdx.x * 256 + threadIdx.x;
  if (n >= N_NODES) return;
  int b = batch[n];
  if (n == 0) {
    for (int bb = 0; bb <= b; ++bb) gstart[bb] = 0;
  } else {
    int pb = batch[n - 1];
    for (int bb = pb + 1; bb <= b; ++bb) gstart[bb] = n;
  }
  if (n == N_NODES - 1)
    for (int bb = b + 1; bb <= NB; ++bb) gstart[bb] = N_NODES;
}

__global__ __launch_bounds__(256) void gsoft_kernel(const float* __restrict__ gate, const int* __restrict__ gstart,
                                                    float* __restrict__ gm, float* __restrict__ ginv) {
  const int b = blockIdx.x, tid = threadIdx.x;
  const int s = gstart[b], e = gstart[b + 1];
  float m = -3.0e38f;
  for (int n = s + tid; n < e; n += 256) m = fmaxf(m, gate[n]);
  for (int o = 32; o > 0; o >>= 1) m = fmaxf(m, __shfl_down(m, o));
  __shared__ float red[4];
  __shared__ float red2[4];
  const int wid = tid >> 6, lane = tid & 63;
  if (lane == 0) red[wid] = m;
  __syncthreads();
  m = fmaxf(fmaxf(red[0], red[1]), fmaxf(red[2], red[3]));
  float sum = 0.f;
  for (int n = s + tid; n < e; n += 256) sum += __expf(gate[n] - m);
  for (int o = 32; o > 0; o >>= 1) sum += __shfl_down(sum, o);
  if (lane == 0) red2[wid] = sum;
  __syncthreads();
  if (tid == 0) {
    sum = red2[0] + red2[1] + red2[2] + red2[3];
    gm[b] = m;
    ginv[b] = 1.0f / fmaxf(sum, 1e-16f);
  }
}

__global__ __launch_bounds__(256) void pool_kernel(const float* __restrict__ out2, const float* __restrict__ gate,
                                                   const float* __restrict__ gm, const float* __restrict__ ginv,
                                                   const int* __restrict__ gstart, float* __restrict__ dout) {
  const int b = blockIdx.y;
  const int col = blockIdx.x * 256 + threadIdx.x;
  const int s = gstart[b], e = gstart[b + 1];
  const float m = gm[b], gi = ginv[b];
  float acc = 0.f;
  for (int n = s; n < e; ++n) {
    float w = __expf(gate[n] - m) * gi;
    acc += w * out2[(size_t)n * OUTD + col];
  }
  dout[(size_t)b * OUTD + col] = acc;
}

// ---------------------------------------------------------------------------
// Workspace layout (bytes)
// ---------------------------------------------------------------------------
#define WS_H12    0            // h1 (67MB) then h2 (134MB) then gate bufs (reused region)
#define WS_GH1    0            // 16.7MB, after h2 dead
#define WS_GH2    33554432     // 16.7MB
#define WS_OUT1   134217728    // 16777216
#define WS_OUT2   150994944    // 33554432
#define WS_Z      184549376    // zero block start
#define WS_DEG    (WS_Z + 0)        // 16384
#define WS_CUR    (WS_Z + 16384)    // 16384
#define WS_AES1   (WS_Z + 32768)    // 65536
#define WS_AES2   (WS_Z + 98304)    // 65536
#define WS_ZBYTES 163840
#define WS_OFFS   (WS_Z + 163840)   // 16640 (int[4097])
#define WS_CSRS   (WS_OFFS + 16640) // 65536
#define WS_CSRE   (WS_CSRS + 65536) // 65536
#define WS_AS1    (WS_CSRE + 65536) // 65536
#define WS_AD1    (WS_AS1 + 65536)
#define WS_AEE1   (WS_AD1 + 65536)  // 262144
#define WS_AS2    (WS_AEE1 + 262144)
#define WS_AD2    (WS_AS2 + 65536)
#define WS_AEE2   (WS_AD2 + 65536)  // 262144
#define WS_V1     (WS_AEE2 + 262144) // 8192
#define WS_V2     (WS_V1 + 8192)
#define WS_GATE   (WS_V2 + 8192)    // 16384
#define WS_GM     (WS_GATE + 16384) // 128
#define WS_GINV   (WS_GM + 128)     // 128
#define WS_GSTART (WS_GINV + 128)   // 256 (int[33])

extern "C" void kernel_launch(void* const* d_in, const int* in_sizes, int n_in,
                              void* d_out, int out_size, void* d_ws, size_t ws_size,
                              hipStream_t stream) {
  const float* x     = (const float*)d_in[0];
  const int*   ei    = (const int*)d_in[1];
  const float* ea    = (const float*)d_in[2];
  const int*   batch = (const int*)d_in[3];
  const float* W1    = (const float*)d_in[4];
  const float* asrc1 = (const float*)d_in[5];
  const float* adst1 = (const float*)d_in[6];
  const float* We1   = (const float*)d_in[7];
  const float* ae1   = (const float*)d_in[8];
  const float* b1    = (const float*)d_in[9];
  const float* p1    = (const float*)d_in[10];
  const float* W2    = (const float*)d_in[11];
  const float* asrc2 = (const float*)d_in[12];
  const float* adst2 = (const float*)d_in[13];
  const float* We2   = (const float*)d_in[14];
  const float* ae2   = (const float*)d_in[15];
  const float* b2    = (const float*)d_in[16];
  const float* p2    = (const float*)d_in[17];
  const float* gW1   = (const float*)d_in[18];
  const float* gb1   = (const float*)d_in[19];
  const float* gp1   = (const float*)d_in[20];
  const float* gW2   = (const float*)d_in[21];
  const float* gb2   = (const float*)d_in[22];
  const float* gp2   = (const float*)d_in[23];
  const float* gW3   = (const float*)d_in[24];
  const float* gb3   = (const float*)d_in[25];

  char* ws = (char*)d_ws;
  float* h1      = (float*)(ws + WS_H12);
  float* h2      = (float*)(ws + WS_H12);
  float* gh1     = (float*)(ws + WS_GH1);
  float* gh2     = (float*)(ws + WS_GH2);
  float* out1    = (float*)(ws + WS_OUT1);
  float* out2    = (float*)(ws + WS_OUT2);
  int*   deg     = (int*)(ws + WS_DEG);
  int*   cursor  = (int*)(ws + WS_CUR);
  float* aesum1  = (float*)(ws + WS_AES1);
  float* aesum2  = (float*)(ws + WS_AES2);
  int*   offs    = (int*)(ws + WS_OFFS);
  int*   csr_src = (int*)(ws + WS_CSRS);
  int*   csr_eid = (int*)(ws + WS_CSRE);
  float* as1     = (float*)(ws + WS_AS1);
  float* ad1     = (float*)(ws + WS_AD1);
  float* aee1    = (float*)(ws + WS_AEE1);
  float* as2     = (float*)(ws + WS_AS2);
  float* ad2     = (float*)(ws + WS_AD2);
  float* aee2    = (float*)(ws + WS_AEE2);
  float* v1      = (float*)(ws + WS_V1);
  float* v2      = (float*)(ws + WS_V2);
  float* gate    = (float*)(ws + WS_GATE);
  float* gm      = (float*)(ws + WS_GM);
  float* ginv    = (float*)(ws + WS_GINV);
  int*   gstart  = (int*)(ws + WS_GSTART);

  float* dout = (float*)d_out;

  // zero accumulators (ws is re-poisoned to 0xAA before every timed launch)
  hipMemsetAsync(ws + WS_Z, 0, WS_ZBYTES, stream);

  // edge-attr attention vectors (both layers)
  v_kernel<HID><<<CLIPD, 256, 0, stream>>>(We1, ae1, v1);
  v_kernel<OUTD><<<CLIPD, 256, 0, stream>>>(We2, ae2, v2);

  // CSR by dst
  deg_kernel<<<N_EDGES / 256, 256, 0, stream>>>(ei, deg);
  scan_kernel<<<1, 1024, 0, stream>>>(deg, offs);
  fill_kernel<<<N_EDGES / 256, 256, 0, stream>>>(ei, offs, cursor, csr_src, csr_eid);

  // h1 = x @ W1
  gemm_kernel<0><<<dim3(64, 64), 256, 0, stream>>>(x, W1, h1, N_NODES, NH * HID, CLIPD, nullptr, nullptr);

  // a_e for both layers + segment sums for self-loop mean
  ae_kernel<<<N_EDGES / 64, 256, 0, stream>>>(ea, ei, v1, v2, aee1, aee2, aesum1, aesum2);
  loopdiv_kernel<<<(N_NODES * NH) / 256, 256, 0, stream>>>(aesum1, aesum2, deg);

  // layer 1 attention + aggregation
  nodedot_kernel<HID><<<N_NODES, 256, 0, stream>>>(h1, asrc1, adst1, as1, ad1);
  agg_kernel<HID><<<N_NODES, 256, 0, stream>>>(h1, as1, ad1, aee1, aesum1, offs, csr_src, csr_eid,
                                               b1, p1, out1);

  // h2 = out1 @ W2
  gemm_kernel<0><<<dim3(128, 64), 256, 0, stream>>>(out1, W2, h2, N_NODES, NH * OUTD, HID, nullptr, nullptr);

  // layer 2 attention + aggregation
  nodedot_kernel<OUTD><<<N_NODES, 256, 0, stream>>>(h2, asrc2, adst2, as2, ad2);
  agg_kernel<OUTD><<<N_NODES, 256, 0, stream>>>(h2, as2, ad2, aee2, aesum2, offs, csr_src, csr_eid,
                                                b2, p2, out2);

  // gate MLP
  gemm_kernel<1><<<dim3(16, 64), 256, 0, stream>>>(out2, gW1, gh1, N_NODES, HID, OUTD, gb1, gp1);
  gemm_kernel<1><<<dim3(16, 64), 256, 0, stream>>>(gh1, gW2, gh2, N_NODES, HID, HID, gb2, gp2);
  gate3_kernel<<<N_NODES, 256, 0, stream>>>(gh2, gW3, gb3, gate);

  // attentional pooling (batch sorted -> contiguous ranges, deterministic)
  gstart_kernel<<<N_NODES / 256, 256, 0, stream>>>(batch, gstart);
  gsoft_kernel<<<NB, 256, 0, stream>>>(gate, gstart, gm, ginv);
  pool_kernel<<<dim3(OUTD / 256, NB), 256, 0, stream>>>(out2, gate, gm, ginv, gstart, dout);
}

// Round 2
// 585.853 us; speedup vs baseline: 3.3543x; 3.3543x over previous
//
#include <hip/hip_runtime.h>
#include <hip/hip_bf16.h>
#include <math.h>

#define N_NODES 4096
#define N_EDGES 16384
#define CLIPD   512
#define HID     1024
#define NH      4
#define OUTD    2048
#define NB      32

typedef __bf16 bf16_t;
typedef bf16_t bf16x8 __attribute__((ext_vector_type(8)));
typedef float f32x4 __attribute__((ext_vector_type(4)));

static __device__ __forceinline__ float lrelu(float x) { return x >= 0.f ? x : 0.2f * x; }

static __device__ __forceinline__ unsigned short f2bf(float f) {
  union { float f; unsigned int u; } v; v.f = f;
  unsigned int u = v.u;
  unsigned int r = (u + 0x7FFFu + ((u >> 16) & 1u)) >> 16;
  return (unsigned short)r;
}
static __device__ __forceinline__ float bf2f(unsigned short u) {
  union { unsigned int i; float f; } v; v.i = ((unsigned int)u) << 16; return v.f;
}

#define GLDS(g, l) __builtin_amdgcn_global_load_lds( \
    (const __attribute__((address_space(1))) void*)(g), \
    (__attribute__((address_space(3))) void*)(l), 16, 0, 0)

// ---------------------------------------------------------------------------
// fp32 -> bf16 elementwise (vectorized 4-wide)
// ---------------------------------------------------------------------------
__global__ __launch_bounds__(256) void cvt_kernel(const float* __restrict__ in,
                                                  unsigned short* __restrict__ out, int n4) {
  int i = blockIdx.x * 256 + threadIdx.x;
  if (i < n4) {
    float4 f = ((const float4*)in)[i];
    ushort4 o;
    o.x = f2bf(f.x); o.y = f2bf(f.y); o.z = f2bf(f.z); o.w = f2bf(f.w);
    ((ushort4*)out)[i] = o;
  }
}

// ---------------------------------------------------------------------------
// fp32 [K][N] -> bf16 [N][K] transpose-convert (32x32 tile)
// ---------------------------------------------------------------------------
__global__ __launch_bounds__(256) void tcvt_kernel(const float* __restrict__ in,
                                                   unsigned short* __restrict__ out,
                                                   int K, int N) {
  __shared__ float t[32][33];
  const int k0 = blockIdx.y * 32, n0 = blockIdx.x * 32;
  const int tx = threadIdx.x, ty = threadIdx.y;
#pragma unroll
  for (int i = 0; i < 4; ++i) t[ty + 8 * i][tx] = in[(size_t)(k0 + ty + 8 * i) * N + n0 + tx];
  __syncthreads();
#pragma unroll
  for (int i = 0; i < 4; ++i) out[(size_t)(n0 + ty + 8 * i) * K + k0 + tx] = f2bf(t[tx][ty + 8 * i]);
}

// ---------------------------------------------------------------------------
// v[k][h] = sum_c We[k][h*C+c] * ae[h*C+c]
// ---------------------------------------------------------------------------
template<int C>
__global__ __launch_bounds__(256) void v_kernel(const float* __restrict__ We,
                                                const float* __restrict__ ae,
                                                float* __restrict__ v) {
  const int k = blockIdx.x;
  const int tid = threadIdx.x;
  const float* row = We + (size_t)k * (NH * C);
  float acc[NH] = {0.f, 0.f, 0.f, 0.f};
  for (int c = tid; c < C; c += 256) {
    for (int h = 0; h < NH; ++h) acc[h] += row[h * C + c] * ae[h * C + c];
  }
  for (int h = 0; h < NH; ++h)
    for (int o = 32; o > 0; o >>= 1) acc[h] += __shfl_down(acc[h], o);
  __shared__ float red[4][NH];
  const int wid = tid >> 6, lane = tid & 63;
  if (lane == 0)
    for (int h = 0; h < NH; ++h) red[wid][h] = acc[h];
  __syncthreads();
  if (tid < NH) v[k * NH + tid] = red[0][tid] + red[1][tid] + red[2][tid] + red[3][tid];
}

// ---------------------------------------------------------------------------
// CSR build
// ---------------------------------------------------------------------------
__global__ void deg_kernel(const int* __restrict__ ei, int* __restrict__ deg) {
  int e = blockIdx.x * 256 + threadIdx.x;
  if (e < N_EDGES) atomicAdd(&deg[ei[N_EDGES + e]], 1);
}

__global__ __launch_bounds__(1024) void scan_kernel(const int* __restrict__ deg, int* __restrict__ offs) {
  __shared__ int s[1024];
  const int t = threadIdx.x;
  int d0 = deg[4 * t], d1 = deg[4 * t + 1], d2 = deg[4 * t + 2], d3 = deg[4 * t + 3];
  s[t] = d0 + d1 + d2 + d3;
  __syncthreads();
  for (int off = 1; off < 1024; off <<= 1) {
    int v = (t >= off) ? s[t - off] : 0;
    __syncthreads();
    s[t] += v;
    __syncthreads();
  }
  int base = (t > 0) ? s[t - 1] : 0;
  offs[4 * t] = base;
  offs[4 * t + 1] = base + d0;
  offs[4 * t + 2] = base + d0 + d1;
  offs[4 * t + 3] = base + d0 + d1 + d2;
  if (t == 1023) offs[4096] = s[1023];
}

__global__ void fill_kernel(const int* __restrict__ ei, const int* __restrict__ offs,
                            int* __restrict__ cursor, int* __restrict__ csr_src,
                            int* __restrict__ csr_eid) {
  int e = blockIdx.x * 256 + threadIdx.x;
  if (e >= N_EDGES) return;
  int dst = ei[N_EDGES + e];
  int pos = offs[dst] + atomicAdd(&cursor[dst], 1);
  csr_src[pos] = ei[e];
  csr_eid[pos] = e;
}

// ---------------------------------------------------------------------------
// a_e for both layers in one pass over edge_attr + segment sums (self-loop mean)
// ---------------------------------------------------------------------------
__global__ __launch_bounds__(256) void ae_kernel(const float* __restrict__ ea, const int* __restrict__ ei,
                                                 const float* __restrict__ v1, const float* __restrict__ v2,
                                                 float* __restrict__ ae1, float* __restrict__ ae2,
                                                 float* __restrict__ aesum1, float* __restrict__ aesum2) {
  __shared__ float4 v1s[CLIPD];
  __shared__ float4 v2s[CLIPD];
  const int tid = threadIdx.x;
  v1s[tid] = ((const float4*)v1)[tid];
  v1s[tid + 256] = ((const float4*)v1)[tid + 256];
  v2s[tid] = ((const float4*)v2)[tid];
  v2s[tid + 256] = ((const float4*)v2)[tid + 256];
  __syncthreads();
  const int wid = tid >> 6, lane = tid & 63;
  for (int i = 0; i < 16; ++i) {
    const int e = blockIdx.x * 64 + wid * 16 + i;
    const float* row = ea + (size_t)e * CLIPD;
    float a1[NH] = {0.f, 0.f, 0.f, 0.f}, a2[NH] = {0.f, 0.f, 0.f, 0.f};
    for (int k = lane; k < CLIPD; k += 64) {
      float x = row[k];
      float4 w1 = v1s[k];
      float4 w2 = v2s[k];
      a1[0] += x * w1.x; a1[1] += x * w1.y; a1[2] += x * w1.z; a1[3] += x * w1.w;
      a2[0] += x * w2.x; a2[1] += x * w2.y; a2[2] += x * w2.z; a2[3] += x * w2.w;
    }
    for (int h = 0; h < NH; ++h)
      for (int o = 32; o > 0; o >>= 1) {
        a1[h] += __shfl_down(a1[h], o);
        a2[h] += __shfl_down(a2[h], o);
      }
    if (lane == 0) {
      int dst = ei[N_EDGES + e];
      for (int h = 0; h < NH; ++h) {
        ae1[e * NH + h] = a1[h];
        ae2[e * NH + h] = a2[h];
        atomicAdd(&aesum1[dst * NH + h], a1[h]);
        atomicAdd(&aesum2[dst * NH + h], a2[h]);
      }
    }
  }
}

__global__ void loopdiv_kernel(float* __restrict__ s1, float* __restrict__ s2,
                               const int* __restrict__ deg) {
  int i = blockIdx.x * 256 + threadIdx.x;
  if (i >= N_NODES * NH) return;
  float c = fmaxf((float)deg[i >> 2], 1.0f);
  s1[i] /= c;
  s2[i] /= c;
}

// ---------------------------------------------------------------------------
// bf16 MFMA GEMM (m97 structure): C[M][N] = A[M][K] @ Bt[N][K]^T
// 128x128 tile, BK=32, 4 waves, 4x4 16x16x32 fragments, global_load_lds w=16.
// EPI=1: bias + prelu.  Output bf16.
// ---------------------------------------------------------------------------
template<int EPI>
__global__ __launch_bounds__(256) void mfma_gemm(const unsigned short* __restrict__ A,
                                                 const unsigned short* __restrict__ Bt,
                                                 unsigned short* __restrict__ C,
                                                 int M, int N, int K,
                                                 const float* __restrict__ bias,
                                                 const float* __restrict__ pa) {
  __shared__ unsigned short As[128 * 32];
  __shared__ unsigned short Bs[128 * 32];
  const int tid = threadIdx.x;
  const int lane = tid & 63;
  const int w = tid >> 6;
  const int wr = w >> 1, wc = w & 1;
  const int brow = blockIdx.y * 128, bcol = blockIdx.x * 128;
  const int r0 = tid >> 2;                 // staging row within 64-row half
  const int koff = (tid & 3) * 8;          // ushort offset within 32-elem row
  const int fr = lane & 15;                // fragment row/col within 16
  const int fk = (lane >> 4) * 8;          // fragment k-offset
  f32x4 acc[4][4] = {};
  for (int kt = 0; kt < K; kt += 32) {
    GLDS(A + (size_t)(brow + r0) * K + kt + koff, &As[tid * 8]);
    GLDS(A + (size_t)(brow + 64 + r0) * K + kt + koff, &As[2048 + tid * 8]);
    GLDS(Bt + (size_t)(bcol + r0) * K + kt + koff, &Bs[tid * 8]);
    GLDS(Bt + (size_t)(bcol + 64 + r0) * K + kt + koff, &Bs[2048 + tid * 8]);
    asm volatile("s_waitcnt vmcnt(0)" ::: "memory");
    __syncthreads();
    bf16x8 af[4], bfr[4];
#pragma unroll
    for (int mi = 0; mi < 4; ++mi)
      af[mi] = *(const bf16x8*)&As[(wr * 64 + mi * 16 + fr) * 32 + fk];
#pragma unroll
    for (int ni = 0; ni < 4; ++ni)
      bfr[ni] = *(const bf16x8*)&Bs[(wc * 64 + ni * 16 + fr) * 32 + fk];
#pragma unroll
    for (int mi = 0; mi < 4; ++mi)
#pragma unroll
      for (int ni = 0; ni < 4; ++ni)
        acc[mi][ni] = __builtin_amdgcn_mfma_f32_16x16x32_bf16(af[mi], bfr[ni], acc[mi][ni], 0, 0, 0);
    __syncthreads();
  }
  const float ap = EPI ? *pa : 0.f;
#pragma unroll
  for (int mi = 0; mi < 4; ++mi) {
    const int rb = brow + wr * 64 + mi * 16 + (lane >> 4) * 4;
#pragma unroll
    for (int ni = 0; ni < 4; ++ni) {
      const int col = bcol + wc * 64 + ni * 16 + fr;
      float bv = 0.f;
      if (EPI) bv = bias[col];
#pragma unroll
      for (int r = 0; r < 4; ++r) {
        float v = acc[mi][ni][r];
        if (EPI) { v += bv; v = v >= 0.f ? v : ap * v; }
        C[(size_t)(rb + r) * N + col] = f2bf(v);
      }
    }
  }
}

// ---------------------------------------------------------------------------
// Per-node attention dots from bf16 h
// ---------------------------------------------------------------------------
template<int C>
__global__ __launch_bounds__(256) void nodedot_kernel(const unsigned short* __restrict__ hbuf,
                                                      const float* __restrict__ asrc,
                                                      const float* __restrict__ adst,
                                                      float* __restrict__ as_, float* __restrict__ ad_) {
  const int n = blockIdx.x, tid = threadIdx.x;
  const unsigned short* row = hbuf + (size_t)n * (NH * C);
  float s[NH] = {0.f, 0.f, 0.f, 0.f}, d[NH] = {0.f, 0.f, 0.f, 0.f};
  for (int c4 = tid; c4 < C / 4; c4 += 256) {
#pragma unroll
    for (int h = 0; h < NH; ++h) {
      ushort4 u = *(const ushort4*)&row[h * C + c4 * 4];
      float4 av = *(const float4*)&asrc[h * C + c4 * 4];
      float4 dv = *(const float4*)&adst[h * C + c4 * 4];
      float f0 = bf2f(u.x), f1 = bf2f(u.y), f2 = bf2f(u.z), f3 = bf2f(u.w);
      s[h] += f0 * av.x + f1 * av.y + f2 * av.z + f3 * av.w;
      d[h] += f0 * dv.x + f1 * dv.y + f2 * dv.z + f3 * dv.w;
    }
  }
  for (int h = 0; h < NH; ++h)
    for (int o = 32; o > 0; o >>= 1) {
      s[h] += __shfl_down(s[h], o);
      d[h] += __shfl_down(d[h], o);
    }
  __shared__ float rs[4][NH], rd[4][NH];
  const int wid = tid >> 6, lane = tid & 63;
  if (lane == 0)
    for (int h = 0; h < NH; ++h) {
      rs[wid][h] = s[h];
      rd[wid][h] = d[h];
    }
  __syncthreads();
  if (tid < NH)
    as_[n * NH + tid] = rs[0][tid] + rs[1][tid] + rs[2][tid] + rs[3][tid];
  else if (tid < 2 * NH) {
    int h = tid - NH;
    ad_[n * NH + h] = rd[0][h] + rd[1][h] + rd[2][h] + rd[3][h];
  }
}

// ---------------------------------------------------------------------------
// Per-node softmax + aggregation from bf16 h. OUTMODE 0: bf16 out only.
// OUTMODE 1: fp32 out + bf16 out.
// ---------------------------------------------------------------------------
template<int C, int OUTMODE>
__global__ __launch_bounds__(256) void agg_kernel(const unsigned short* __restrict__ hbuf,
                                                  const float* __restrict__ as_, const float* __restrict__ ad_,
                                                  const float* __restrict__ aee, const float* __restrict__ aeloop,
                                                  const int* __restrict__ offs, const int* __restrict__ csr_src,
                                                  const int* __restrict__ csr_eid,
                                                  const float* __restrict__ bias, const float* __restrict__ pa,
                                                  float* __restrict__ outf, unsigned short* __restrict__ outb) {
  constexpr int HC = NH * C;
  constexpr int C4 = C / 1024;        // ushort4-chunks per head per thread
  const int n = blockIdx.x;
  const int tid = threadIdx.x;
  const int off = offs[n];
  const int deg = offs[n + 1] - off;
  __shared__ float minv[NH], dinv[NH], wself[NH];
  __shared__ float wch[32][NH];
  __shared__ int sch[32];
  if (tid < 64) {
    const int h = tid >> 4, slot = tid & 15;
    const float adn = ad_[n * NH + h];
    const float aself = lrelu(as_[n * NH + h] + adn + aeloop[n * NH + h]);
    float m = (slot == 0) ? aself : -3.0e38f;
    for (int i = slot; i < deg; i += 16) {
      float a = lrelu(as_[csr_src[off + i] * NH + h] + adn + aee[csr_eid[off + i] * NH + h]);
      m = fmaxf(m, a);
    }
    for (int o = 1; o < 16; o <<= 1) m = fmaxf(m, __shfl_xor(m, o));
    float den = (slot == 0) ? __expf(aself - m) : 0.f;
    for (int i = slot; i < deg; i += 16) {
      float a = lrelu(as_[csr_src[off + i] * NH + h] + adn + aee[csr_eid[off + i] * NH + h]);
      den += __expf(a - m);
    }
    for (int o = 1; o < 16; o <<= 1) den += __shfl_xor(den, o);
    if (slot == 0) {
      minv[h] = m;
      dinv[h] = 1.0f / den;
      wself[h] = __expf(aself - m) / den;
    }
  }
  __syncthreads();
  float acc[NH][C4 * 4];
#pragma unroll
  for (int h = 0; h < NH; ++h)
#pragma unroll
    for (int c = 0; c < C4 * 4; ++c) acc[h][c] = 0.f;
  for (int base = 0; base < deg; base += 32) {
    const int cnt = min(32, deg - base);
    if (tid < cnt * NH) {
      const int i = tid >> 2, h = tid & 3;
      const int sidx = csr_src[off + base + i];
      float a = lrelu(as_[sidx * NH + h] + ad_[n * NH + h] + aee[csr_eid[off + base + i] * NH + h]);
      wch[i][h] = __expf(a - minv[h]) * dinv[h];
      if (h == 0) sch[i] = sidx;
    }
    __syncthreads();
    for (int i = 0; i < cnt; ++i) {
      const unsigned short* hp = hbuf + (size_t)sch[i] * HC;
#pragma unroll
      for (int h = 0; h < NH; ++h) {
        const float wv = wch[i][h];
#pragma unroll
        for (int c = 0; c < C4; ++c) {
          ushort4 u = *(const ushort4*)&hp[h * C + (c * 256 + tid) * 4];
          acc[h][c * 4 + 0] += wv * bf2f(u.x);
          acc[h][c * 4 + 1] += wv * bf2f(u.y);
          acc[h][c * 4 + 2] += wv * bf2f(u.z);
          acc[h][c * 4 + 3] += wv * bf2f(u.w);
        }
      }
    }
    __syncthreads();
  }
  {
    const unsigned short* hp = hbuf + (size_t)n * HC;
#pragma unroll
    for (int h = 0; h < NH; ++h) {
      const float wv = wself[h];
#pragma unroll
      for (int c = 0; c < C4; ++c) {
        ushort4 u = *(const ushort4*)&hp[h * C + (c * 256 + tid) * 4];
        acc[h][c * 4 + 0] += wv * bf2f(u.x);
        acc[h][c * 4 + 1] += wv * bf2f(u.y);
        acc[h][c * 4 + 2] += wv * bf2f(u.z);
        acc[h][c * 4 + 3] += wv * bf2f(u.w);
      }
    }
  }
  const float ap = *pa;
#pragma unroll
  for (int c = 0; c < C4; ++c) {
    const int cb = (c * 256 + tid) * 4;
    float4 vf;
    ushort4 vb;
    float* vp = &vf.x;
#pragma unroll
    for (int j = 0; j < 4; ++j) {
      float v = 0.25f * (acc[0][c * 4 + j] + acc[1][c * 4 + j] + acc[2][c * 4 + j] + acc[3][c * 4 + j])
                + bias[cb + j];
      v = v >= 0.f ? v : ap * v;
      vp[j] = v;
    }
    vb.x = f2bf(vf.x); vb.y = f2bf(vf.y); vb.z = f2bf(vf.z); vb.w = f2bf(vf.w);
    if (OUTMODE == 1) *(float4*)&outf[(size_t)n * C + cb] = vf;
    *(ushort4*)&outb[(size_t)n * C + cb] = vb;
  }
}

// ---------------------------------------------------------------------------
// gate = gh2 @ gW3 + gb3 (bf16 matvec)
// ---------------------------------------------------------------------------
__global__ __launch_bounds__(256) void gate3_kernel(const unsigned short* __restrict__ gh2,
                                                    const float* __restrict__ gW3,
                                                    const float* __restrict__ gb3, float* __restrict__ gate) {
  const int n = blockIdx.x, tid = threadIdx.x;
  const unsigned short* row = gh2 + (size_t)n * HID;
  ushort4 u = *(const ushort4*)&row[tid * 4];
  float4 wv = *(const float4*)&gW3[tid * 4];
  float acc = bf2f(u.x) * wv.x + bf2f(u.y) * wv.y + bf2f(u.z) * wv.z + bf2f(u.w) * wv.w;
  for (int o = 32; o > 0; o >>= 1) acc += __shfl_down(acc, o);
  __shared__ float red[4];
  const int wid = tid >> 6, lane = tid & 63;
  if (lane == 0) red[wid] = acc;
  __syncthreads();
  if (tid == 0) gate[n] = red[0] + red[1] + red[2] + red[3] + gb3[0];
}

__global__ void gstart_kernel(const int* __restrict__ batch, int* __restrict__ gstart) {
  int n = blockIdx.x * 256 + threadIdx.x;
  if (n >= N_NODES) return;
  int b = batch[n];
  if (n == 0) {
    for (int bb = 0; bb <= b; ++bb) gstart[bb] = 0;
  } else {
    int pb = batch[n - 1];
    for (int bb = pb + 1; bb <= b; ++bb) gstart[bb] = n;
  }
  if (n == N_NODES - 1)
    for (int bb = b + 1; bb <= NB; ++bb) gstart[bb] = N_NODES;
}

__global__ __launch_bounds__(256) void gsoft_kernel(const float* __restrict__ gate, const int* __restrict__ gstart,
                                                    float* __restrict__ gm, float* __restrict__ ginv) {
  const int b = blockIdx.x, tid = threadIdx.x;
  const int s = gstart[b], e = gstart[b + 1];
  float m = -3.0e38f;
  for (int n = s + tid; n < e; n += 256) m = fmaxf(m, gate[n]);
  for (int o = 32; o > 0; o >>= 1) m = fmaxf(m, __shfl_down(m, o));
  __shared__ float red[4];
  __shared__ float red2[4];
  const int wid = tid >> 6, lane = tid & 63;
  if (lane == 0) red[wid] = m;
  __syncthreads();
  m = fmaxf(fmaxf(red[0], red[1]), fmaxf(red[2], red[3]));
  float sum = 0.f;
  for (int n = s + tid; n < e; n += 256) sum += __expf(gate[n] - m);
  for (int o = 32; o > 0; o >>= 1) sum += __shfl_down(sum, o);
  if (lane == 0) red2[wid] = sum;
  __syncthreads();
  if (tid == 0) {
    sum = red2[0] + red2[1] + red2[2] + red2[3];
    gm[b] = m;
    ginv[b] = 1.0f / fmaxf(sum, 1e-16f);
  }
}

__global__ __launch_bounds__(256) void pool_kernel(const float* __restrict__ out2, const float* __restrict__ gate,
                                                   const float* __restrict__ gm, const float* __restrict__ ginv,
                                                   const int* __restrict__ gstart, float* __restrict__ dout) {
  const int b = blockIdx.y;
  const int col = blockIdx.x * 256 + threadIdx.x;
  const int s = gstart[b], e = gstart[b + 1];
  const float m = gm[b], gi = ginv[b];
  float acc = 0.f;
  for (int n = s; n < e; ++n) {
    float w = __expf(gate[n] - m) * gi;
    acc += w * out2[(size_t)n * OUTD + col];
  }
  dout[(size_t)b * OUTD + col] = acc;
}

// ---------------------------------------------------------------------------
// Workspace layout (bytes). Region [0,64MB) holds {xb, W1t, h1b} first, then
// is reused for h2b after they are dead (stream-ordered).
// ---------------------------------------------------------------------------
#define MB(x) ((size_t)(x) * 1048576)
#define WS_XB     MB(0)     // 4 MB   bf16 x [4096][512]
#define WS_W1T    MB(4)     // 4 MB   bf16 W1^T [4096][512]
#define WS_H1B    MB(8)     // 32 MB  bf16 h1 [4096][4096]
#define WS_H2B    MB(0)     // 64 MB  bf16 h2 [4096][8192] (reuses region)
#define WS_OUT1B  MB(64)    // 8 MB   bf16 out1 [4096][1024]
#define WS_W2T    MB(72)    // 16 MB  bf16 W2^T [8192][1024]
#define WS_OUT2F  MB(88)    // 32 MB  fp32 out2 [4096][2048]
#define WS_OUT2B  MB(120)   // 16 MB  bf16 out2
#define WS_GH1B   MB(136)   // 8 MB   bf16 gh1 [4096][1024]
#define WS_GH2B   MB(144)   // 8 MB   bf16 gh2
#define WS_GW1T   MB(152)   // 4 MB   bf16 gW1^T [1024][2048]
#define WS_GW2T   MB(156)   // 2 MB   bf16 gW2^T [1024][1024]
#define WS_SM     MB(158)
#define WS_DEG    (WS_SM + 0)
#define WS_CUR    (WS_SM + 16384)
#define WS_AES1   (WS_SM + 32768)
#define WS_AES2   (WS_SM + 98304)
#define WS_ZBYTES 163840
#define WS_OFFS   (WS_SM + 163840)
#define WS_CSRS   (WS_OFFS + 16640)
#define WS_CSRE   (WS_CSRS + 65536)
#define WS_AS1    (WS_CSRE + 65536)
#define WS_AD1    (WS_AS1 + 65536)
#define WS_AEE1   (WS_AD1 + 65536)
#define WS_AS2    (WS_AEE1 + 262144)
#define WS_AD2    (WS_AS2 + 65536)
#define WS_AEE2   (WS_AD2 + 65536)
#define WS_V1     (WS_AEE2 + 262144)
#define WS_V2     (WS_V1 + 8192)
#define WS_GATE   (WS_V2 + 8192)
#define WS_GM     (WS_GATE + 16384)
#define WS_GINV   (WS_GM + 128)
#define WS_GSTART (WS_GINV + 128)

extern "C" void kernel_launch(void* const* d_in, const int* in_sizes, int n_in,
                              void* d_out, int out_size, void* d_ws, size_t ws_size,
                              hipStream_t stream) {
  const float* x     = (const float*)d_in[0];
  const int*   ei    = (const int*)d_in[1];
  const float* ea    = (const float*)d_in[2];
  const int*   batch = (const int*)d_in[3];
  const float* W1    = (const float*)d_in[4];
  const float* asrc1 = (const float*)d_in[5];
  const float* adst1 = (const float*)d_in[6];
  const float* We1   = (const float*)d_in[7];
  const float* ae1w  = (const float*)d_in[8];
  const float* b1    = (const float*)d_in[9];
  const float* p1    = (const float*)d_in[10];
  const float* W2    = (const float*)d_in[11];
  const float* asrc2 = (const float*)d_in[12];
  const float* adst2 = (const float*)d_in[13];
  const float* We2   = (const float*)d_in[14];
  const float* ae2w  = (const float*)d_in[15];
  const float* b2    = (const float*)d_in[16];
  const float* p2    = (const float*)d_in[17];
  const float* gW1   = (const float*)d_in[18];
  const float* gb1   = (const float*)d_in[19];
  const float* gp1   = (const float*)d_in[20];
  const float* gW2   = (const float*)d_in[21];
  const float* gb2   = (const float*)d_in[22];
  const float* gp2   = (const float*)d_in[23];
  const float* gW3   = (const float*)d_in[24];
  const float* gb3   = (const float*)d_in[25];

  char* ws = (char*)d_ws;
  unsigned short* xb    = (unsigned short*)(ws + WS_XB);
  unsigned short* W1t   = (unsigned short*)(ws + WS_W1T);
  unsigned short* h1b   = (unsigned short*)(ws + WS_H1B);
  unsigned short* h2b   = (unsigned short*)(ws + WS_H2B);
  unsigned short* out1b = (unsigned short*)(ws + WS_OUT1B);
  unsigned short* W2t   = (unsigned short*)(ws + WS_W2T);
  float*          out2f = (float*)(ws + WS_OUT2F);
  unsigned short* out2b = (unsigned short*)(ws + WS_OUT2B);
  unsigned short* gh1b  = (unsigned short*)(ws + WS_GH1B);
  unsigned short* gh2b  = (unsigned short*)(ws + WS_GH2B);
  unsigned short* gW1t  = (unsigned short*)(ws + WS_GW1T);
  unsigned short* gW2t  = (unsigned short*)(ws + WS_GW2T);
  int*   deg     = (int*)(ws + WS_DEG);
  int*   cursor  = (int*)(ws + WS_CUR);
  float* aesum1  = (float*)(ws + WS_AES1);
  float* aesum2  = (float*)(ws + WS_AES2);
  int*   offs    = (int*)(ws + WS_OFFS);
  int*   csr_src = (int*)(ws + WS_CSRS);
  int*   csr_eid = (int*)(ws + WS_CSRE);
  float* as1     = (float*)(ws + WS_AS1);
  float* ad1     = (float*)(ws + WS_AD1);
  float* aee1    = (float*)(ws + WS_AEE1);
  float* as2     = (float*)(ws + WS_AS2);
  float* ad2     = (float*)(ws + WS_AD2);
  float* aee2    = (float*)(ws + WS_AEE2);
  float* v1      = (float*)(ws + WS_V1);
  float* v2      = (float*)(ws + WS_V2);
  float* gate    = (float*)(ws + WS_GATE);
  float* gm      = (float*)(ws + WS_GM);
  float* ginv    = (float*)(ws + WS_GINV);
  int*   gstart  = (int*)(ws + WS_GSTART);
  float* dout    = (float*)d_out;

  hipMemsetAsync(ws + WS_DEG, 0, WS_ZBYTES, stream);

  // convert inputs/weights to bf16 (weights transposed to [N][K])
  cvt_kernel<<<(N_NODES * CLIPD / 4 + 255) / 256, 256, 0, stream>>>(x, xb, N_NODES * CLIPD / 4);
  tcvt_kernel<<<dim3(4096 / 32, 512 / 32), dim3(32, 8), 0, stream>>>(W1, W1t, CLIPD, NH * HID);
  tcvt_kernel<<<dim3(8192 / 32, 1024 / 32), dim3(32, 8), 0, stream>>>(W2, W2t, HID, NH * OUTD);
  tcvt_kernel<<<dim3(1024 / 32, 2048 / 32), dim3(32, 8), 0, stream>>>(gW1, gW1t, OUTD, HID);
  tcvt_kernel<<<dim3(1024 / 32, 1024 / 32), dim3(32, 8), 0, stream>>>(gW2, gW2t, HID, HID);

  // edge-attr attention vectors (both layers)
  v_kernel<HID><<<CLIPD, 256, 0, stream>>>(We1, ae1w, v1);
  v_kernel<OUTD><<<CLIPD, 256, 0, stream>>>(We2, ae2w, v2);

  // CSR by dst
  deg_kernel<<<N_EDGES / 256, 256, 0, stream>>>(ei, deg);
  scan_kernel<<<1, 1024, 0, stream>>>(deg, offs);
  fill_kernel<<<N_EDGES / 256, 256, 0, stream>>>(ei, offs, cursor, csr_src, csr_eid);

  // h1 = x @ W1  (bf16 MFMA)
  mfma_gemm<0><<<dim3(32, 32), 256, 0, stream>>>(xb, W1t, h1b, N_NODES, NH * HID, CLIPD, nullptr, nullptr);

  // a_e both layers + self-loop means
  ae_kernel<<<N_EDGES / 64, 256, 0, stream>>>(ea, ei, v1, v2, aee1, aee2, aesum1, aesum2);
  loopdiv_kernel<<<(N_NODES * NH) / 256, 256, 0, stream>>>(aesum1, aesum2, deg);

  // layer 1 attention + aggregation
  nodedot_kernel<HID><<<N_NODES, 256, 0, stream>>>(h1b, asrc1, adst1, as1, ad1);
  agg_kernel<HID, 0><<<N_NODES, 256, 0, stream>>>(h1b, as1, ad1, aee1, aesum1, offs, csr_src, csr_eid,
                                                  b1, p1, nullptr, out1b);

  // h2 = out1 @ W2
  mfma_gemm<0><<<dim3(64, 32), 256, 0, stream>>>(out1b, W2t, h2b, N_NODES, NH * OUTD, HID, nullptr, nullptr);

  // layer 2 attention + aggregation
  nodedot_kernel<OUTD><<<N_NODES, 256, 0, stream>>>(h2b, asrc2, adst2, as2, ad2);
  agg_kernel<OUTD, 1><<<N_NODES, 256, 0, stream>>>(h2b, as2, ad2, aee2, aesum2, offs, csr_src, csr_eid,
                                                   b2, p2, out2f, out2b);

  // gate MLP (bf16 MFMA with fused bias+prelu)
  mfma_gemm<1><<<dim3(8, 32), 256, 0, stream>>>(out2b, gW1t, gh1b, N_NODES, HID, OUTD, gb1, gp1);
  mfma_gemm<1><<<dim3(8, 32), 256, 0, stream>>>(gh1b, gW2t, gh2b, N_NODES, HID, HID, gb2, gp2);
  gate3_kernel<<<N_NODES, 256, 0, stream>>>(gh2b, gW3, gb3, gate);

  // attentional pooling
  gstart_kernel<<<N_NODES / 256, 256, 0, stream>>>(batch, gstart);
  gsoft_kernel<<<NB, 256, 0, stream>>>(gate, gstart, gm, ginv);
  pool_kernel<<<dim3(OUTD / 256, NB), 256, 0, stream>>>(out2f, gate, gm, ginv, gstart, dout);
}

// Round 3
// 558.986 us; speedup vs baseline: 3.5156x; 1.0481x over previous
//
#include <hip/hip_runtime.h>
#include <hip/hip_bf16.h>
#include <math.h>

#define N_NODES 4096
#define N_EDGES 16384
#define CLIPD   512
#define HID     1024
#define NH      4
#define OUTD    2048
#define NB      32

typedef __bf16 bf16_t;
typedef bf16_t bf16x8 __attribute__((ext_vector_type(8)));
typedef float f32x4 __attribute__((ext_vector_type(4)));

static __device__ __forceinline__ float lrelu(float x) { return x >= 0.f ? x : 0.2f * x; }

static __device__ __forceinline__ unsigned short f2bf(float f) {
  union { float f; unsigned int u; } v; v.f = f;
  unsigned int u = v.u;
  unsigned int r = (u + 0x7FFFu + ((u >> 16) & 1u)) >> 16;
  return (unsigned short)r;
}
static __device__ __forceinline__ float bf2f(unsigned short u) {
  union { unsigned int i; float f; } v; v.i = ((unsigned int)u) << 16; return v.f;
}

#define GLDS(g, l) __builtin_amdgcn_global_load_lds( \
    (const __attribute__((address_space(1))) void*)(g), \
    (__attribute__((address_space(3))) void*)(l), 16, 0, 0)

// ---------------------------------------------------------------------------
// fp32 -> bf16 elementwise
// ---------------------------------------------------------------------------
__global__ __launch_bounds__(256) void cvt_kernel(const float* __restrict__ in,
                                                  unsigned short* __restrict__ out, int n4) {
  int i = blockIdx.x * 256 + threadIdx.x;
  if (i < n4) {
    float4 f = ((const float4*)in)[i];
    ushort4 o;
    o.x = f2bf(f.x); o.y = f2bf(f.y); o.z = f2bf(f.z); o.w = f2bf(f.w);
    ((ushort4*)out)[i] = o;
  }
}

// ---------------------------------------------------------------------------
// plain fp32 [K][N] -> bf16 [N][K] transpose-convert
// ---------------------------------------------------------------------------
__global__ __launch_bounds__(256) void tcvt_kernel(const float* __restrict__ in,
                                                   unsigned short* __restrict__ out,
                                                   int K, int N) {
  __shared__ float t[32][33];
  const int k0 = blockIdx.y * 32, n0 = blockIdx.x * 32;
  const int tx = threadIdx.x, ty = threadIdx.y;
#pragma unroll
  for (int i = 0; i < 4; ++i) t[ty + 8 * i][tx] = in[(size_t)(k0 + ty + 8 * i) * N + n0 + tx];
  __syncthreads();
#pragma unroll
  for (int i = 0; i < 4; ++i) out[(size_t)(n0 + ty + 8 * i) * K + k0 + tx] = f2bf(t[tx][ty + 8 * i]);
}

// ---------------------------------------------------------------------------
// Head-stacked transpose-convert with scale:
// in [K1][NH*N1] (fp32, per-head blocks of N1) -> out [N1][NH*K1] (bf16)
// out[n][h*K1+k] = scale * in[k][h*N1+n]
// ---------------------------------------------------------------------------
template<int K1, int N1>
__global__ __launch_bounds__(256) void stack_tcvt_kernel(const float* __restrict__ in,
                                                         unsigned short* __restrict__ out,
                                                         float scale) {
  __shared__ float t[32][33];
  const int h = blockIdx.z;
  const int k0 = blockIdx.y * 32, n0 = blockIdx.x * 32;
  const int tx = threadIdx.x, ty = threadIdx.y;
#pragma unroll
  for (int i = 0; i < 4; ++i)
    t[ty + 8 * i][tx] = in[(size_t)(k0 + ty + 8 * i) * (NH * N1) + h * N1 + n0 + tx];
  __syncthreads();
#pragma unroll
  for (int i = 0; i < 4; ++i)
    out[(size_t)(n0 + ty + 8 * i) * (NH * K1) + h * K1 + k0 + tx] = f2bf(scale * t[tx][ty + 8 * i]);
}

// ---------------------------------------------------------------------------
// v[k][h] = sum_c W[k][h*C+c] * a[h*C+c]   (fold attention vec through W)
// ---------------------------------------------------------------------------
template<int C>
__global__ __launch_bounds__(256) void v_kernel(const float* __restrict__ W,
                                                const float* __restrict__ a,
                                                float* __restrict__ v) {
  const int k = blockIdx.x;
  const int tid = threadIdx.x;
  const float* row = W + (size_t)k * (NH * C);
  float acc[NH] = {0.f, 0.f, 0.f, 0.f};
  for (int c = tid; c < C; c += 256) {
    for (int h = 0; h < NH; ++h) acc[h] += row[h * C + c] * a[h * C + c];
  }
  for (int h = 0; h < NH; ++h)
    for (int o = 32; o > 0; o >>= 1) acc[h] += __shfl_down(acc[h], o);
  __shared__ float red[4][NH];
  const int wid = tid >> 6, lane = tid & 63;
  if (lane == 0)
    for (int h = 0; h < NH; ++h) red[wid][h] = acc[h];
  __syncthreads();
  if (tid < NH) v[k * NH + tid] = red[0][tid] + red[1][tid] + red[2][tid] + red[3][tid];
}

// dual version: one pass over W, two attention vectors
template<int C>
__global__ __launch_bounds__(256) void v2_kernel(const float* __restrict__ W,
                                                 const float* __restrict__ a1v,
                                                 const float* __restrict__ a2v,
                                                 float* __restrict__ o1, float* __restrict__ o2) {
  const int k = blockIdx.x;
  const int tid = threadIdx.x;
  const float* row = W + (size_t)k * (NH * C);
  float x1[NH] = {0.f, 0.f, 0.f, 0.f}, x2[NH] = {0.f, 0.f, 0.f, 0.f};
  for (int c = tid; c < C; c += 256) {
    for (int h = 0; h < NH; ++h) {
      float w = row[h * C + c];
      x1[h] += w * a1v[h * C + c];
      x2[h] += w * a2v[h * C + c];
    }
  }
  for (int h = 0; h < NH; ++h)
    for (int o = 32; o > 0; o >>= 1) {
      x1[h] += __shfl_down(x1[h], o);
      x2[h] += __shfl_down(x2[h], o);
    }
  __shared__ float r1[4][NH], r2[4][NH];
  const int wid = tid >> 6, lane = tid & 63;
  if (lane == 0)
    for (int h = 0; h < NH; ++h) { r1[wid][h] = x1[h]; r2[wid][h] = x2[h]; }
  __syncthreads();
  if (tid < NH) o1[k * NH + tid] = r1[0][tid] + r1[1][tid] + r1[2][tid] + r1[3][tid];
  else if (tid < 2 * NH) {
    int h = tid - NH;
    o2[k * NH + h] = r2[0][h] + r2[1][h] + r2[2][h] + r2[3][h];
  }
}

// ---------------------------------------------------------------------------
// CSR build
// ---------------------------------------------------------------------------
__global__ void deg_kernel(const int* __restrict__ ei, int* __restrict__ deg) {
  int e = blockIdx.x * 256 + threadIdx.x;
  if (e < N_EDGES) atomicAdd(&deg[ei[N_EDGES + e]], 1);
}

__global__ __launch_bounds__(1024) void scan_kernel(const int* __restrict__ deg, int* __restrict__ offs) {
  __shared__ int s[1024];
  const int t = threadIdx.x;
  int d0 = deg[4 * t], d1 = deg[4 * t + 1], d2 = deg[4 * t + 2], d3 = deg[4 * t + 3];
  s[t] = d0 + d1 + d2 + d3;
  __syncthreads();
  for (int off = 1; off < 1024; off <<= 1) {
    int v = (t >= off) ? s[t - off] : 0;
    __syncthreads();
    s[t] += v;
    __syncthreads();
  }
  int base = (t > 0) ? s[t - 1] : 0;
  offs[4 * t] = base;
  offs[4 * t + 1] = base + d0;
  offs[4 * t + 2] = base + d0 + d1;
  offs[4 * t + 3] = base + d0 + d1 + d2;
  if (t == 1023) offs[4096] = s[1023];
}

__global__ void fill_kernel(const int* __restrict__ ei, const int* __restrict__ offs,
                            int* __restrict__ cursor, int* __restrict__ csr_src,
                            int* __restrict__ csr_eid) {
  int e = blockIdx.x * 256 + threadIdx.x;
  if (e >= N_EDGES) return;
  int dst = ei[N_EDGES + e];
  int pos = offs[dst] + atomicAdd(&cursor[dst], 1);
  csr_src[pos] = ei[e];
  csr_eid[pos] = e;
}

// ---------------------------------------------------------------------------
// a_e for both layers in one pass over edge_attr + segment sums (self-loop mean)
// ---------------------------------------------------------------------------
__global__ __launch_bounds__(256) void ae_kernel(const float* __restrict__ ea, const int* __restrict__ ei,
                                                 const float* __restrict__ v1, const float* __restrict__ v2,
                                                 float* __restrict__ ae1, float* __restrict__ ae2,
                                                 float* __restrict__ aesum1, float* __restrict__ aesum2) {
  __shared__ float4 v1s[CLIPD];
  __shared__ float4 v2s[CLIPD];
  const int tid = threadIdx.x;
  v1s[tid] = ((const float4*)v1)[tid];
  v1s[tid + 256] = ((const float4*)v1)[tid + 256];
  v2s[tid] = ((const float4*)v2)[tid];
  v2s[tid + 256] = ((const float4*)v2)[tid + 256];
  __syncthreads();
  const int wid = tid >> 6, lane = tid & 63;
  for (int i = 0; i < 16; ++i) {
    const int e = blockIdx.x * 64 + wid * 16 + i;
    const float* row = ea + (size_t)e * CLIPD;
    float a1[NH] = {0.f, 0.f, 0.f, 0.f}, a2[NH] = {0.f, 0.f, 0.f, 0.f};
    for (int k = lane; k < CLIPD; k += 64) {
      float x = row[k];
      float4 w1 = v1s[k];
      float4 w2 = v2s[k];
      a1[0] += x * w1.x; a1[1] += x * w1.y; a1[2] += x * w1.z; a1[3] += x * w1.w;
      a2[0] += x * w2.x; a2[1] += x * w2.y; a2[2] += x * w2.z; a2[3] += x * w2.w;
    }
    for (int h = 0; h < NH; ++h)
      for (int o = 32; o > 0; o >>= 1) {
        a1[h] += __shfl_down(a1[h], o);
        a2[h] += __shfl_down(a2[h], o);
      }
    if (lane == 0) {
      int dst = ei[N_EDGES + e];
      for (int h = 0; h < NH; ++h) {
        ae1[e * NH + h] = a1[h];
        ae2[e * NH + h] = a2[h];
        atomicAdd(&aesum1[dst * NH + h], a1[h]);
        atomicAdd(&aesum2[dst * NH + h], a2[h]);
      }
    }
  }
}

__global__ void loopdiv_kernel(float* __restrict__ s1, float* __restrict__ s2,
                               const int* __restrict__ deg) {
  int i = blockIdx.x * 256 + threadIdx.x;
  if (i >= N_NODES * NH) return;
  float c = fmaxf((float)deg[i >> 2], 1.0f);
  s1[i] /= c;
  s2[i] /= c;
}

// ---------------------------------------------------------------------------
// Node attention dots: layer-1 (fp32 x, C=512), one wave per row
// a_s[n][h] = x[n]·us[:,h],  a_d[n][h] = x[n]·ud[:,h]
// ---------------------------------------------------------------------------
__global__ __launch_bounds__(256) void rowdot_x(const float* __restrict__ x,
                                                const float* __restrict__ us, const float* __restrict__ ud,
                                                float* __restrict__ as_, float* __restrict__ ad_) {
  __shared__ float4 su[CLIPD], sd[CLIPD];
  const int tid = threadIdx.x;
  for (int k = tid; k < CLIPD; k += 256) {
    su[k] = ((const float4*)us)[k];
    sd[k] = ((const float4*)ud)[k];
  }
  __syncthreads();
  const int wid = tid >> 6, lane = tid & 63;
  const int n = blockIdx.x * 4 + wid;
  const float* row = x + (size_t)n * CLIPD;
  float s[NH] = {0.f, 0.f, 0.f, 0.f}, d[NH] = {0.f, 0.f, 0.f, 0.f};
  for (int k = lane; k < CLIPD; k += 64) {
    float xv = row[k];
    float4 u = su[k], v = sd[k];
    s[0] += xv * u.x; s[1] += xv * u.y; s[2] += xv * u.z; s[3] += xv * u.w;
    d[0] += xv * v.x; d[1] += xv * v.y; d[2] += xv * v.z; d[3] += xv * v.w;
  }
#pragma unroll
  for (int h = 0; h < NH; ++h)
    for (int o = 32; o > 0; o >>= 1) {
      s[h] += __shfl_down(s[h], o);
      d[h] += __shfl_down(d[h], o);
    }
  if (lane == 0)
    for (int h = 0; h < NH; ++h) {
      as_[n * NH + h] = s[h];
      ad_[n * NH + h] = d[h];
    }
}

// layer-2: bf16 out1 rows, C=1024
__global__ __launch_bounds__(256) void rowdot_o(const unsigned short* __restrict__ rows,
                                                const float* __restrict__ us, const float* __restrict__ ud,
                                                float* __restrict__ as_, float* __restrict__ ad_) {
  __shared__ float4 su[HID], sd[HID];
  const int tid = threadIdx.x;
  for (int k = tid; k < HID; k += 256) {
    su[k] = ((const float4*)us)[k];
    sd[k] = ((const float4*)ud)[k];
  }
  __syncthreads();
  const int wid = tid >> 6, lane = tid & 63;
  const int n = blockIdx.x * 4 + wid;
  const unsigned short* row = rows + (size_t)n * HID;
  float s[NH] = {0.f, 0.f, 0.f, 0.f}, d[NH] = {0.f, 0.f, 0.f, 0.f};
  for (int k2 = lane; k2 < HID / 2; k2 += 64) {
    ushort2 uv = ((const ushort2*)row)[k2];
    float f0 = bf2f(uv.x), f1 = bf2f(uv.y);
    float4 u0 = su[2 * k2], u1 = su[2 * k2 + 1];
    float4 v0 = sd[2 * k2], v1 = sd[2 * k2 + 1];
    s[0] += f0 * u0.x + f1 * u1.x; s[1] += f0 * u0.y + f1 * u1.y;
    s[2] += f0 * u0.z + f1 * u1.z; s[3] += f0 * u0.w + f1 * u1.w;
    d[0] += f0 * v0.x + f1 * v1.x; d[1] += f0 * v0.y + f1 * v1.y;
    d[2] += f0 * v0.z + f1 * v1.z; d[3] += f0 * v0.w + f1 * v1.w;
  }
#pragma unroll
  for (int h = 0; h < NH; ++h)
    for (int o = 32; o > 0; o >>= 1) {
      s[h] += __shfl_down(s[h], o);
      d[h] += __shfl_down(d[h], o);
    }
  if (lane == 0)
    for (int h = 0; h < NH; ++h) {
      as_[n * NH + h] = s[h];
      ad_[n * NH + h] = d[h];
    }
}

// ---------------------------------------------------------------------------
// Narrow per-head aggregation in the INPUT domain (pre-W):
// out[n][h*C+c] = sum_e w[e][h]*src[src_e][c] + wself[h]*src[n][c]
// (softmax over in-edges incl. self-loop; mean-over-heads is folded into the
//  0.25-scaled stacked weights of the following GEMM)
// ---------------------------------------------------------------------------
template<int C>
__global__ __launch_bounds__(256) void aggn_kernel(const unsigned short* __restrict__ src,
                                                   const float* __restrict__ as_, const float* __restrict__ ad_,
                                                   const float* __restrict__ aee, const float* __restrict__ aeloop,
                                                   const int* __restrict__ offs, const int* __restrict__ csr_src,
                                                   const int* __restrict__ csr_eid,
                                                   unsigned short* __restrict__ out) {
  constexpr int CPT = C / 256;   // 2 (C=512) or 4 (C=1024)
  const int n = blockIdx.x;
  const int tid = threadIdx.x;
  const int off = offs[n];
  const int deg = offs[n + 1] - off;
  __shared__ float minv[NH], dinv[NH], wself[NH];
  __shared__ float wch[32][NH];
  __shared__ int sch[32];
  if (tid < 64) {
    const int h = tid >> 4, slot = tid & 15;
    const float adn = ad_[n * NH + h];
    const float aself = lrelu(as_[n * NH + h] + adn + aeloop[n * NH + h]);
    float m = (slot == 0) ? aself : -3.0e38f;
    for (int i = slot; i < deg; i += 16) {
      float a = lrelu(as_[csr_src[off + i] * NH + h] + adn + aee[csr_eid[off + i] * NH + h]);
      m = fmaxf(m, a);
    }
    for (int o = 1; o < 16; o <<= 1) m = fmaxf(m, __shfl_xor(m, o));
    float den = (slot == 0) ? __expf(aself - m) : 0.f;
    for (int i = slot; i < deg; i += 16) {
      float a = lrelu(as_[csr_src[off + i] * NH + h] + adn + aee[csr_eid[off + i] * NH + h]);
      den += __expf(a - m);
    }
    for (int o = 1; o < 16; o <<= 1) den += __shfl_xor(den, o);
    if (slot == 0) {
      minv[h] = m;
      dinv[h] = 1.0f / den;
      wself[h] = __expf(aself - m) / den;
    }
  }
  __syncthreads();
  float acc[NH][CPT];
#pragma unroll
  for (int h = 0; h < NH; ++h)
#pragma unroll
    for (int c = 0; c < CPT; ++c) acc[h][c] = 0.f;
  for (int base = 0; base < deg; base += 32) {
    const int cnt = min(32, deg - base);
    if (tid < cnt * NH) {
      const int i = tid >> 2, h = tid & 3;
      const int sidx = csr_src[off + base + i];
      float a = lrelu(as_[sidx * NH + h] + ad_[n * NH + h] + aee[csr_eid[off + base + i] * NH + h]);
      wch[i][h] = __expf(a - minv[h]) * dinv[h];
      if (h == 0) sch[i] = sidx;
    }
    __syncthreads();
    for (int i = 0; i < cnt; ++i) {
      const unsigned short* hp = src + (size_t)sch[i] * C + tid * CPT;
      float f[CPT];
      if constexpr (CPT == 2) {
        ushort2 u = *(const ushort2*)hp;
        f[0] = bf2f(u.x); f[1] = bf2f(u.y);
      } else {
        ushort4 u = *(const ushort4*)hp;
        f[0] = bf2f(u.x); f[1] = bf2f(u.y); f[2] = bf2f(u.z); f[3] = bf2f(u.w);
      }
#pragma unroll
      for (int h = 0; h < NH; ++h) {
        const float wv = wch[i][h];
#pragma unroll
        for (int c = 0; c < CPT; ++c) acc[h][c] += wv * f[c];
      }
    }
    __syncthreads();
  }
  {
    const unsigned short* hp = src + (size_t)n * C + tid * CPT;
    float f[CPT];
    if constexpr (CPT == 2) {
      ushort2 u = *(const ushort2*)hp;
      f[0] = bf2f(u.x); f[1] = bf2f(u.y);
    } else {
      ushort4 u = *(const ushort4*)hp;
      f[0] = bf2f(u.x); f[1] = bf2f(u.y); f[2] = bf2f(u.z); f[3] = bf2f(u.w);
    }
#pragma unroll
    for (int h = 0; h < NH; ++h) {
      const float wv = wself[h];
#pragma unroll
      for (int c = 0; c < CPT; ++c) acc[h][c] += wv * f[c];
    }
  }
#pragma unroll
  for (int h = 0; h < NH; ++h) {
    if constexpr (CPT == 2) {
      ushort2 o;
      o.x = f2bf(acc[h][0]); o.y = f2bf(acc[h][1]);
      *(ushort2*)&out[((size_t)n * NH + h) * C + tid * 2] = o;
    } else {
      ushort4 o;
      o.x = f2bf(acc[h][0]); o.y = f2bf(acc[h][1]); o.z = f2bf(acc[h][2]); o.w = f2bf(acc[h][3]);
      *(ushort4*)&out[((size_t)n * NH + h) * C + tid * 4] = o;
    }
  }
}

// ---------------------------------------------------------------------------
// bf16 MFMA GEMM (m97 structure): C[M][N] = A[M][K] @ Bt[N][K]^T
// EPI=1: bias + prelu.  WF=1: also write fp32.
// ---------------------------------------------------------------------------
template<int EPI, int WF>
__global__ __launch_bounds__(256) void mfma_gemm(const unsigned short* __restrict__ A,
                                                 const unsigned short* __restrict__ Bt,
                                                 unsigned short* __restrict__ C,
                                                 float* __restrict__ Cf,
                                                 int M, int N, int K,
                                                 const float* __restrict__ bias,
                                                 const float* __restrict__ pa) {
  __shared__ unsigned short As[128 * 32];
  __shared__ unsigned short Bs[128 * 32];
  const int tid = threadIdx.x;
  const int lane = tid & 63;
  const int w = tid >> 6;
  const int wr = w >> 1, wc = w & 1;
  const int brow = blockIdx.y * 128, bcol = blockIdx.x * 128;
  const int r0 = tid >> 2;
  const int koff = (tid & 3) * 8;
  const int fr = lane & 15;
  const int fk = (lane >> 4) * 8;
  f32x4 acc[4][4] = {};
  for (int kt = 0; kt < K; kt += 32) {
    GLDS(A + (size_t)(brow + r0) * K + kt + koff, &As[tid * 8]);
    GLDS(A + (size_t)(brow + 64 + r0) * K + kt + koff, &As[2048 + tid * 8]);
    GLDS(Bt + (size_t)(bcol + r0) * K + kt + koff, &Bs[tid * 8]);
    GLDS(Bt + (size_t)(bcol + 64 + r0) * K + kt + koff, &Bs[2048 + tid * 8]);
    asm volatile("s_waitcnt vmcnt(0)" ::: "memory");
    __syncthreads();
    bf16x8 af[4], bfr[4];
#pragma unroll
    for (int mi = 0; mi < 4; ++mi)
      af[mi] = *(const bf16x8*)&As[(wr * 64 + mi * 16 + fr) * 32 + fk];
#pragma unroll
    for (int ni = 0; ni < 4; ++ni)
      bfr[ni] = *(const bf16x8*)&Bs[(wc * 64 + ni * 16 + fr) * 32 + fk];
#pragma unroll
    for (int mi = 0; mi < 4; ++mi)
#pragma unroll
      for (int ni = 0; ni < 4; ++ni)
        acc[mi][ni] = __builtin_amdgcn_mfma_f32_16x16x32_bf16(af[mi], bfr[ni], acc[mi][ni], 0, 0, 0);
    __syncthreads();
  }
  const float ap = EPI ? *pa : 0.f;
#pragma unroll
  for (int mi = 0; mi < 4; ++mi) {
    const int rb = brow + wr * 64 + mi * 16 + (lane >> 4) * 4;
#pragma unroll
    for (int ni = 0; ni < 4; ++ni) {
      const int col = bcol + wc * 64 + ni * 16 + fr;
      float bv = 0.f;
      if (EPI) bv = bias[col];
#pragma unroll
      for (int r = 0; r < 4; ++r) {
        float v = acc[mi][ni][r];
        if (EPI) { v += bv; v = v >= 0.f ? v : ap * v; }
        C[(size_t)(rb + r) * N + col] = f2bf(v);
        if (WF) Cf[(size_t)(rb + r) * N + col] = v;
      }
    }
  }
}

// ---------------------------------------------------------------------------
// gate = gh2 @ gW3 + gb3 (bf16 matvec)
// ---------------------------------------------------------------------------
__global__ __launch_bounds__(256) void gate3_kernel(const unsigned short* __restrict__ gh2,
                                                    const float* __restrict__ gW3,
                                                    const float* __restrict__ gb3, float* __restrict__ gate) {
  const int n = blockIdx.x, tid = threadIdx.x;
  const unsigned short* row = gh2 + (size_t)n * HID;
  ushort4 u = *(const ushort4*)&row[tid * 4];
  float4 wv = *(const float4*)&gW3[tid * 4];
  float acc = bf2f(u.x) * wv.x + bf2f(u.y) * wv.y + bf2f(u.z) * wv.z + bf2f(u.w) * wv.w;
  for (int o = 32; o > 0; o >>= 1) acc += __shfl_down(acc, o);
  __shared__ float red[4];
  const int wid = tid >> 6, lane = tid & 63;
  if (lane == 0) red[wid] = acc;
  __syncthreads();
  if (tid == 0) gate[n] = red[0] + red[1] + red[2] + red[3] + gb3[0];
}

__global__ void gstart_kernel(const int* __restrict__ batch, int* __restrict__ gstart) {
  int n = blockIdx.x * 256 + threadIdx.x;
  if (n >= N_NODES) return;
  int b = batch[n];
  if (n == 0) {
    for (int bb = 0; bb <= b; ++bb) gstart[bb] = 0;
  } else {
    int pb = batch[n - 1];
    for (int bb = pb + 1; bb <= b; ++bb) gstart[bb] = n;
  }
  if (n == N_NODES - 1)
    for (int bb = b + 1; bb <= NB; ++bb) gstart[bb] = N_NODES;
}

__global__ __launch_bounds__(256) void gsoft_kernel(const float* __restrict__ gate, const int* __restrict__ gstart,
                                                    float* __restrict__ gm, float* __restrict__ ginv) {
  const int b = blockIdx.x, tid = threadIdx.x;
  const int s = gstart[b], e = gstart[b + 1];
  float m = -3.0e38f;
  for (int n = s + tid; n < e; n += 256) m = fmaxf(m, gate[n]);
  for (int o = 32; o > 0; o >>= 1) m = fmaxf(m, __shfl_down(m, o));
  __shared__ float red[4];
  __shared__ float red2[4];
  const int wid = tid >> 6, lane = tid & 63;
  if (lane == 0) red[wid] = m;
  __syncthreads();
  m = fmaxf(fmaxf(red[0], red[1]), fmaxf(red[2], red[3]));
  float sum = 0.f;
  for (int n = s + tid; n < e; n += 256) sum += __expf(gate[n] - m);
  for (int o = 32; o > 0; o >>= 1) sum += __shfl_down(sum, o);
  if (lane == 0) red2[wid] = sum;
  __syncthreads();
  if (tid == 0) {
    sum = red2[0] + red2[1] + red2[2] + red2[3];
    gm[b] = m;
    ginv[b] = 1.0f / fmaxf(sum, 1e-16f);
  }
}

__global__ __launch_bounds__(256) void pool_kernel(const float* __restrict__ out2, const float* __restrict__ gate,
                                                   const float* __restrict__ gm, const float* __restrict__ ginv,
                                                   const int* __restrict__ gstart, float* __restrict__ dout) {
  const int b = blockIdx.y;
  const int col = blockIdx.x * 256 + threadIdx.x;
  const int s = gstart[b], e = gstart[b + 1];
  const float m = gm[b], gi = ginv[b];
  float acc = 0.f;
  for (int n = s; n < e; ++n) {
    float w = __expf(gate[n] - m) * gi;
    acc += w * out2[(size_t)n * OUTD + col];
  }
  dout[(size_t)b * OUTD + col] = acc;
}

// ---------------------------------------------------------------------------
// Workspace layout
// ---------------------------------------------------------------------------
#define MB(x) ((size_t)(x) * 1048576)
#define WS_XB     MB(0)     // 4 MB   bf16 x [4096][512]
#define WS_B1T    MB(4)     // 4 MB   bf16 stacked 0.25*W1^T [1024][2048]
#define WS_B2T    MB(8)     // 16 MB  bf16 stacked 0.25*W2^T [2048][4096]
#define WS_GW1T   MB(24)    // 4 MB   bf16 gW1^T [1024][2048]
#define WS_GW2T   MB(28)    // 2 MB   bf16 gW2^T [1024][1024]
#define WS_AGGX   MB(30)    // 16 MB  bf16 aggX [4096][2048]
#define WS_OUT1B  MB(46)    // 8 MB   bf16 out1 [4096][1024]
#define WS_AGGO   MB(54)    // 32 MB  bf16 aggO [4096][4096]
#define WS_OUT2F  MB(86)    // 32 MB  fp32 out2 [4096][2048]
#define WS_OUT2B  MB(118)   // 16 MB  bf16 out2
#define WS_GH1B   MB(134)   // 8 MB   bf16 gh1 [4096][1024]
#define WS_GH2B   MB(142)   // 8 MB   bf16 gh2
#define WS_SM     MB(150)
#define WS_DEG    (WS_SM + 0)
#define WS_CUR    (WS_SM + 16384)
#define WS_AES1   (WS_SM + 32768)
#define WS_AES2   (WS_SM + 98304)
#define WS_ZBYTES 163840
#define WS_OFFS   (WS_SM + 163840)
#define WS_CSRS   (WS_OFFS + 16640)
#define WS_CSRE   (WS_CSRS + 65536)
#define WS_AS1    (WS_CSRE + 65536)
#define WS_AD1    (WS_AS1 + 65536)
#define WS_AEE1   (WS_AD1 + 65536)
#define WS_AS2    (WS_AEE1 + 262144)
#define WS_AD2    (WS_AS2 + 65536)
#define WS_AEE2   (WS_AD2 + 65536)
#define WS_V1     (WS_AEE2 + 262144)
#define WS_V2     (WS_V1 + 8192)
#define WS_US1    (WS_V2 + 8192)
#define WS_UD1    (WS_US1 + 8192)
#define WS_US2    (WS_UD1 + 8192)
#define WS_UD2    (WS_US2 + 16384)
#define WS_GATE   (WS_UD2 + 16384)
#define WS_GM     (WS_GATE + 16384)
#define WS_GINV   (WS_GM + 128)
#define WS_GSTART (WS_GINV + 128)

extern "C" void kernel_launch(void* const* d_in, const int* in_sizes, int n_in,
                              void* d_out, int out_size, void* d_ws, size_t ws_size,
                              hipStream_t stream) {
  const float* x     = (const float*)d_in[0];
  const int*   ei    = (const int*)d_in[1];
  const float* ea    = (const float*)d_in[2];
  const int*   batch = (const int*)d_in[3];
  const float* W1    = (const float*)d_in[4];
  const float* asrc1 = (const float*)d_in[5];
  const float* adst1 = (const float*)d_in[6];
  const float* We1   = (const float*)d_in[7];
  const float* ae1w  = (const float*)d_in[8];
  const float* b1    = (const float*)d_in[9];
  const float* p1    = (const float*)d_in[10];
  const float* W2    = (const float*)d_in[11];
  const float* asrc2 = (const float*)d_in[12];
  const float* adst2 = (const float*)d_in[13];
  const float* We2   = (const float*)d_in[14];
  const float* ae2w  = (const float*)d_in[15];
  const float* b2    = (const float*)d_in[16];
  const float* p2    = (const float*)d_in[17];
  const float* gW1   = (const float*)d_in[18];
  const float* gb1   = (const float*)d_in[19];
  const float* gp1   = (const float*)d_in[20];
  const float* gW2   = (const float*)d_in[21];
  const float* gb2   = (const float*)d_in[22];
  const float* gp2   = (const float*)d_in[23];
  const float* gW3   = (const float*)d_in[24];
  const float* gb3   = (const float*)d_in[25];

  char* ws = (char*)d_ws;
  unsigned short* xb    = (unsigned short*)(ws + WS_XB);
  unsigned short* B1t   = (unsigned short*)(ws + WS_B1T);
  unsigned short* B2t   = (unsigned short*)(ws + WS_B2T);
  unsigned short* gW1t  = (unsigned short*)(ws + WS_GW1T);
  unsigned short* gW2t  = (unsigned short*)(ws + WS_GW2T);
  unsigned short* aggXb = (unsigned short*)(ws + WS_AGGX);
  unsigned short* out1b = (unsigned short*)(ws + WS_OUT1B);
  unsigned short* aggOb = (unsigned short*)(ws + WS_AGGO);
  float*          out2f = (float*)(ws + WS_OUT2F);
  unsigned short* out2b = (unsigned short*)(ws + WS_OUT2B);
  unsigned short* gh1b  = (unsigned short*)(ws + WS_GH1B);
  unsigned short* gh2b  = (unsigned short*)(ws + WS_GH2B);
  int*   deg     = (int*)(ws + WS_DEG);
  int*   cursor  = (int*)(ws + WS_CUR);
  float* aesum1  = (float*)(ws + WS_AES1);
  float* aesum2  = (float*)(ws + WS_AES2);
  int*   offs    = (int*)(ws + WS_OFFS);
  int*   csr_src = (int*)(ws + WS_CSRS);
  int*   csr_eid = (int*)(ws + WS_CSRE);
  float* as1     = (float*)(ws + WS_AS1);
  float* ad1     = (float*)(ws + WS_AD1);
  float* aee1    = (float*)(ws + WS_AEE1);
  float* as2     = (float*)(ws + WS_AS2);
  float* ad2     = (float*)(ws + WS_AD2);
  float* aee2    = (float*)(ws + WS_AEE2);
  float* v1      = (float*)(ws + WS_V1);
  float* v2      = (float*)(ws + WS_V2);
  float* us1     = (float*)(ws + WS_US1);
  float* ud1     = (float*)(ws + WS_UD1);
  float* us2     = (float*)(ws + WS_US2);
  float* ud2     = (float*)(ws + WS_UD2);
  float* gate    = (float*)(ws + WS_GATE);
  float* gm      = (float*)(ws + WS_GM);
  float* ginv    = (float*)(ws + WS_GINV);
  int*   gstart  = (int*)(ws + WS_GSTART);
  float* dout    = (float*)d_out;

  hipMemsetAsync(ws + WS_DEG, 0, WS_ZBYTES, stream);

  // input/weight conversions
  cvt_kernel<<<(N_NODES * CLIPD / 4 + 255) / 256, 256, 0, stream>>>(x, xb, N_NODES * CLIPD / 4);
  stack_tcvt_kernel<CLIPD, HID><<<dim3(HID / 32, CLIPD / 32, NH), dim3(32, 8), 0, stream>>>(W1, B1t, 0.25f);
  stack_tcvt_kernel<HID, OUTD><<<dim3(OUTD / 32, HID / 32, NH), dim3(32, 8), 0, stream>>>(W2, B2t, 0.25f);
  tcvt_kernel<<<dim3(HID / 32, OUTD / 32), dim3(32, 8), 0, stream>>>(gW1, gW1t, OUTD, HID);
  tcvt_kernel<<<dim3(HID / 32, HID / 32), dim3(32, 8), 0, stream>>>(gW2, gW2t, HID, HID);

  // fold attention vectors through the weights
  v_kernel<HID><<<CLIPD, 256, 0, stream>>>(We1, ae1w, v1);
  v_kernel<OUTD><<<CLIPD, 256, 0, stream>>>(We2, ae2w, v2);
  v2_kernel<HID><<<CLIPD, 256, 0, stream>>>(W1, asrc1, adst1, us1, ud1);
  v2_kernel<OUTD><<<HID, 256, 0, stream>>>(W2, asrc2, adst2, us2, ud2);

  // CSR by dst
  deg_kernel<<<N_EDGES / 256, 256, 0, stream>>>(ei, deg);
  scan_kernel<<<1, 1024, 0, stream>>>(deg, offs);
  fill_kernel<<<N_EDGES / 256, 256, 0, stream>>>(ei, offs, cursor, csr_src, csr_eid);

  // edge attention terms + self-loop means
  ae_kernel<<<N_EDGES / 64, 256, 0, stream>>>(ea, ei, v1, v2, aee1, aee2, aesum1, aesum2);
  loopdiv_kernel<<<(N_NODES * NH) / 256, 256, 0, stream>>>(aesum1, aesum2, deg);

  // layer 1: logits from x, aggregate x, then GEMM through stacked W1
  rowdot_x<<<N_NODES / 4, 256, 0, stream>>>(x, us1, ud1, as1, ad1);
  aggn_kernel<CLIPD><<<N_NODES, 256, 0, stream>>>(xb, as1, ad1, aee1, aesum1, offs, csr_src, csr_eid, aggXb);
  mfma_gemm<1, 0><<<dim3(HID / 128, N_NODES / 128), 256, 0, stream>>>(
      aggXb, B1t, out1b, nullptr, N_NODES, HID, NH * CLIPD, b1, p1);

  // layer 2: logits from out1, aggregate out1, GEMM through stacked W2
  rowdot_o<<<N_NODES / 4, 256, 0, stream>>>(out1b, us2, ud2, as2, ad2);
  aggn_kernel<HID><<<N_NODES, 256, 0, stream>>>(out1b, as2, ad2, aee2, aesum2, offs, csr_src, csr_eid, aggOb);
  mfma_gemm<1, 1><<<dim3(OUTD / 128, N_NODES / 128), 256, 0, stream>>>(
      aggOb, B2t, out2b, out2f, N_NODES, OUTD, NH * HID, b2, p2);

  // gate MLP
  mfma_gemm<1, 0><<<dim3(HID / 128, N_NODES / 128), 256, 0, stream>>>(
      out2b, gW1t, gh1b, nullptr, N_NODES, HID, OUTD, gb1, gp1);
  mfma_gemm<1, 0><<<dim3(HID / 128, N_NODES / 128), 256, 0, stream>>>(
      gh1b, gW2t, gh2b, nullptr, N_NODES, HID, HID, gb2, gp2);
  gate3_kernel<<<N_NODES, 256, 0, stream>>>(gh2b, gW3, gb3, gate);

  // attentional pooling
  gstart_kernel<<<N_NODES / 256, 256, 0, stream>>>(batch, gstart);
  gsoft_kernel<<<NB, 256, 0, stream>>>(gate, gstart, gm, ginv);
  pool_kernel<<<dim3(OUTD / 256, NB), 256, 0, stream>>>(out2f, gate, gm, ginv, gstart, dout);
}

// Round 4
// 543.670 us; speedup vs baseline: 3.6146x; 1.0282x over previous
//
#include <hip/hip_runtime.h>
#include <hip/hip_bf16.h>
#include <math.h>

#define N_NODES 4096
#define N_EDGES 16384
#define CLIPD   512
#define HID     1024
#define NH      4
#define OUTD    2048
#define NB      32

typedef __bf16 bf16_t;
typedef bf16_t bf16x8 __attribute__((ext_vector_type(8)));
typedef float f32x4 __attribute__((ext_vector_type(4)));

static __device__ __forceinline__ float lrelu(float x) { return x >= 0.f ? x : 0.2f * x; }

static __device__ __forceinline__ unsigned short f2bf(float f) {
  union { float f; unsigned int u; } v; v.f = f;
  unsigned int u = v.u;
  unsigned int r = (u + 0x7FFFu + ((u >> 16) & 1u)) >> 16;
  return (unsigned short)r;
}
static __device__ __forceinline__ float bf2f(unsigned short u) {
  union { unsigned int i; float f; } v; v.i = ((unsigned int)u) << 16; return v.f;
}

#define GLDS(g, l) __builtin_amdgcn_global_load_lds( \
    (const __attribute__((address_space(1))) void*)(g), \
    (__attribute__((address_space(3))) void*)(l), 16, 0, 0)

// ---------------------------------------------------------------------------
// wprep: all weight transpose-converts in ONE kernel.
// stcvt semantics: in [K1][NHH*N1] fp32 -> out [N1][NHH*K1] bf16, *scale
// ---------------------------------------------------------------------------
__device__ __forceinline__ void stcvt_tile(float (*t)[33], const float* __restrict__ in,
                                           unsigned short* __restrict__ out,
                                           int K1, int N1, int NHH, int h, int bx, int by,
                                           float scale) {
  const int k0 = by * 32, n0 = bx * 32;
  const int tx = threadIdx.x, ty = threadIdx.y;
#pragma unroll
  for (int i = 0; i < 4; ++i)
    t[ty + 8 * i][tx] = in[(size_t)(k0 + ty + 8 * i) * (NHH * N1) + (size_t)h * N1 + n0 + tx];
  __syncthreads();
#pragma unroll
  for (int i = 0; i < 4; ++i)
    out[(size_t)(n0 + ty + 8 * i) * (NHH * K1) + (size_t)h * K1 + k0 + tx] =
        f2bf(scale * t[tx][ty + 8 * i]);
}

__global__ __launch_bounds__(256) void wprep_kernel(const float* __restrict__ W1, const float* __restrict__ W2,
                                                    const float* __restrict__ gW1, const float* __restrict__ gW2,
                                                    unsigned short* __restrict__ B1t, unsigned short* __restrict__ B2t,
                                                    unsigned short* __restrict__ gW1t, unsigned short* __restrict__ gW2t) {
  __shared__ float t[32][33];
  const int id = blockIdx.x;
  if (id < 2048) {                 // W1 stacked 0.25x: K1=512, N1=1024, NH=4
    int h = id >> 9, r = id & 511;
    stcvt_tile(t, W1, B1t, CLIPD, HID, NH, h, r & 31, r >> 5, 0.25f);
  } else if (id < 10240) {         // W2 stacked 0.25x: K1=1024, N1=2048, NH=4
    int r2 = id - 2048;
    int h = r2 >> 11, r = r2 & 2047;
    stcvt_tile(t, W2, B2t, HID, OUTD, NH, h, r & 63, r >> 6, 0.25f);
  } else if (id < 12288) {         // gW1: K=2048, N=1024
    int r = id - 10240;
    stcvt_tile(t, gW1, gW1t, OUTD, HID, 1, 0, r & 31, r >> 5, 1.0f);
  } else {                         // gW2: K=1024, N=1024
    int r = id - 12288;
    stcvt_tile(t, gW2, gW2t, HID, HID, 1, 0, r & 31, r >> 5, 1.0f);
  }
}

// ---------------------------------------------------------------------------
// vprep: all attention-vector folds in ONE kernel.
// o1[k][h] = sum_c W[k][h*C+c]*a1[h*C+c]; o2 likewise (if non-null)
// ---------------------------------------------------------------------------
__device__ __forceinline__ void vfold(float (*r1)[NH], float (*r2)[NH],
                                      const float* __restrict__ W,
                                      const float* __restrict__ a1v, const float* __restrict__ a2v,
                                      float* __restrict__ o1, float* __restrict__ o2, int C, int k) {
  const int tid = threadIdx.x;
  const float* row = W + (size_t)k * (NH * C);
  float x1[NH] = {0.f, 0.f, 0.f, 0.f}, x2[NH] = {0.f, 0.f, 0.f, 0.f};
  for (int c = tid; c < C; c += 256) {
    for (int h = 0; h < NH; ++h) {
      float w = row[h * C + c];
      x1[h] += w * a1v[h * C + c];
      x2[h] += w * a2v[h * C + c];
    }
  }
  for (int h = 0; h < NH; ++h)
    for (int o = 32; o > 0; o >>= 1) {
      x1[h] += __shfl_down(x1[h], o);
      x2[h] += __shfl_down(x2[h], o);
    }
  const int wid = tid >> 6, lane = tid & 63;
  if (lane == 0)
    for (int h = 0; h < NH; ++h) { r1[wid][h] = x1[h]; r2[wid][h] = x2[h]; }
  __syncthreads();
  if (tid < NH)
    o1[k * NH + tid] = r1[0][tid] + r1[1][tid] + r1[2][tid] + r1[3][tid];
  else if (o2 != nullptr && tid < 2 * NH) {
    int h = tid - NH;
    o2[k * NH + h] = r2[0][h] + r2[1][h] + r2[2][h] + r2[3][h];
  }
}

__global__ __launch_bounds__(256) void vprep_kernel(const float* __restrict__ We1, const float* __restrict__ ae1w,
                                                    const float* __restrict__ We2, const float* __restrict__ ae2w,
                                                    const float* __restrict__ W1, const float* __restrict__ asrc1,
                                                    const float* __restrict__ adst1,
                                                    const float* __restrict__ W2, const float* __restrict__ asrc2,
                                                    const float* __restrict__ adst2,
                                                    float* __restrict__ v1, float* __restrict__ v2,
                                                    float* __restrict__ us1, float* __restrict__ ud1,
                                                    float* __restrict__ us2, float* __restrict__ ud2) {
  __shared__ float r1[4][NH], r2[4][NH];
  const int id = blockIdx.x;
  if (id < 512)       vfold(r1, r2, We1, ae1w, ae1w, v1, nullptr, HID, id);
  else if (id < 1024) vfold(r1, r2, We2, ae2w, ae2w, v2, nullptr, OUTD, id - 512);
  else if (id < 1536) vfold(r1, r2, W1, asrc1, adst1, us1, ud1, HID, id - 1024);
  else                vfold(r1, r2, W2, asrc2, adst2, us2, ud2, OUTD, id - 1536);
}

// ---------------------------------------------------------------------------
// Single-block CSR build: degree count + scan + fill, all in LDS.
// ---------------------------------------------------------------------------
__global__ __launch_bounds__(1024) void csr_kernel(const int* __restrict__ ei,
                                                   int* __restrict__ offs,
                                                   int* __restrict__ csr_src, int* __restrict__ csr_eid) {
  __shared__ int sdeg[N_NODES];
  __shared__ int soffs[N_NODES];
  __shared__ int sscan[1024];
  const int t = threadIdx.x;
  for (int i = t; i < N_NODES; i += 1024) sdeg[i] = 0;
  __syncthreads();
  for (int e = t; e < N_EDGES; e += 1024) atomicAdd(&sdeg[ei[N_EDGES + e]], 1);
  __syncthreads();
  const int d0 = sdeg[4 * t], d1 = sdeg[4 * t + 1], d2 = sdeg[4 * t + 2], d3 = sdeg[4 * t + 3];
  sscan[t] = d0 + d1 + d2 + d3;
  __syncthreads();
  for (int off = 1; off < 1024; off <<= 1) {
    int v = (t >= off) ? sscan[t - off] : 0;
    __syncthreads();
    sscan[t] += v;
    __syncthreads();
  }
  const int base = (t > 0) ? sscan[t - 1] : 0;
  soffs[4 * t] = base;
  soffs[4 * t + 1] = base + d0;
  soffs[4 * t + 2] = base + d0 + d1;
  soffs[4 * t + 3] = base + d0 + d1 + d2;
#pragma unroll
  for (int j = 0; j < 4; ++j) offs[4 * t + j] = soffs[4 * t + j];
  if (t == 1023) offs[N_NODES] = sscan[1023];
  // reuse sdeg as cursor
  sdeg[4 * t] = 0; sdeg[4 * t + 1] = 0; sdeg[4 * t + 2] = 0; sdeg[4 * t + 3] = 0;
  __syncthreads();
  for (int e = t; e < N_EDGES; e += 1024) {
    int dst = ei[N_EDGES + e];
    int pos = soffs[dst] + atomicAdd(&sdeg[dst], 1);
    csr_src[pos] = ei[e];
    csr_eid[pos] = e;
  }
}

// ---------------------------------------------------------------------------
// a_e for both layers in one pass over edge_attr + segment sums (self-loop mean)
// ---------------------------------------------------------------------------
__global__ __launch_bounds__(256) void ae_kernel(const float* __restrict__ ea, const int* __restrict__ ei,
                                                 const float* __restrict__ v1, const float* __restrict__ v2,
                                                 float* __restrict__ ae1, float* __restrict__ ae2,
                                                 float* __restrict__ aesum1, float* __restrict__ aesum2) {
  __shared__ float4 v1s[CLIPD];
  __shared__ float4 v2s[CLIPD];
  const int tid = threadIdx.x;
  v1s[tid] = ((const float4*)v1)[tid];
  v1s[tid + 256] = ((const float4*)v1)[tid + 256];
  v2s[tid] = ((const float4*)v2)[tid];
  v2s[tid + 256] = ((const float4*)v2)[tid + 256];
  __syncthreads();
  const int wid = tid >> 6, lane = tid & 63;
  for (int i = 0; i < 16; ++i) {
    const int e = blockIdx.x * 64 + wid * 16 + i;
    const float* row = ea + (size_t)e * CLIPD;
    float a1[NH] = {0.f, 0.f, 0.f, 0.f}, a2[NH] = {0.f, 0.f, 0.f, 0.f};
    for (int k = lane; k < CLIPD; k += 64) {
      float x = row[k];
      float4 w1 = v1s[k];
      float4 w2 = v2s[k];
      a1[0] += x * w1.x; a1[1] += x * w1.y; a1[2] += x * w1.z; a1[3] += x * w1.w;
      a2[0] += x * w2.x; a2[1] += x * w2.y; a2[2] += x * w2.z; a2[3] += x * w2.w;
    }
    for (int h = 0; h < NH; ++h)
      for (int o = 32; o > 0; o >>= 1) {
        a1[h] += __shfl_down(a1[h], o);
        a2[h] += __shfl_down(a2[h], o);
      }
    if (lane == 0) {
      int dst = ei[N_EDGES + e];
      for (int h = 0; h < NH; ++h) {
        ae1[e * NH + h] = a1[h];
        ae2[e * NH + h] = a2[h];
        atomicAdd(&aesum1[dst * NH + h], a1[h]);
        atomicAdd(&aesum2[dst * NH + h], a2[h]);
      }
    }
  }
}

// ---------------------------------------------------------------------------
// xprep: x -> bf16 copy + per-node attention dots (one pass over x)
// ---------------------------------------------------------------------------
__global__ __launch_bounds__(256) void xprep_kernel(const float* __restrict__ x,
                                                    const float* __restrict__ us, const float* __restrict__ ud,
                                                    unsigned short* __restrict__ xb,
                                                    float* __restrict__ as_, float* __restrict__ ad_) {
  __shared__ float4 su[CLIPD], sd[CLIPD];
  const int tid = threadIdx.x;
  for (int k = tid; k < CLIPD; k += 256) {
    su[k] = ((const float4*)us)[k];
    sd[k] = ((const float4*)ud)[k];
  }
  __syncthreads();
  const int wid = tid >> 6, lane = tid & 63;
  const int n = blockIdx.x * 4 + wid;
  const float* row = x + (size_t)n * CLIPD;
  unsigned short* orow = xb + (size_t)n * CLIPD;
  float s[NH] = {0.f, 0.f, 0.f, 0.f}, d[NH] = {0.f, 0.f, 0.f, 0.f};
  for (int q = lane; q < CLIPD / 4; q += 64) {
    float4 xv = ((const float4*)row)[q];
    ushort4 ob;
    ob.x = f2bf(xv.x); ob.y = f2bf(xv.y); ob.z = f2bf(xv.z); ob.w = f2bf(xv.w);
    ((ushort4*)orow)[q] = ob;
    const float* xp = &xv.x;
#pragma unroll
    for (int j = 0; j < 4; ++j) {
      float xs = xp[j];
      float4 u = su[q * 4 + j], v = sd[q * 4 + j];
      s[0] += xs * u.x; s[1] += xs * u.y; s[2] += xs * u.z; s[3] += xs * u.w;
      d[0] += xs * v.x; d[1] += xs * v.y; d[2] += xs * v.z; d[3] += xs * v.w;
    }
  }
#pragma unroll
  for (int h = 0; h < NH; ++h)
    for (int o = 32; o > 0; o >>= 1) {
      s[h] += __shfl_down(s[h], o);
      d[h] += __shfl_down(d[h], o);
    }
  if (lane == 0)
    for (int h = 0; h < NH; ++h) {
      as_[n * NH + h] = s[h];
      ad_[n * NH + h] = d[h];
    }
}

// layer-2 node dots: bf16 out1 rows, C=1024
__global__ __launch_bounds__(256) void rowdot_o(const unsigned short* __restrict__ rows,
                                                const float* __restrict__ us, const float* __restrict__ ud,
                                                float* __restrict__ as_, float* __restrict__ ad_) {
  __shared__ float4 su[HID], sd[HID];
  const int tid = threadIdx.x;
  for (int k = tid; k < HID; k += 256) {
    su[k] = ((const float4*)us)[k];
    sd[k] = ((const float4*)ud)[k];
  }
  __syncthreads();
  const int wid = tid >> 6, lane = tid & 63;
  const int n = blockIdx.x * 4 + wid;
  const unsigned short* row = rows + (size_t)n * HID;
  float s[NH] = {0.f, 0.f, 0.f, 0.f}, d[NH] = {0.f, 0.f, 0.f, 0.f};
  for (int k2 = lane; k2 < HID / 2; k2 += 64) {
    ushort2 uv = ((const ushort2*)row)[k2];
    float f0 = bf2f(uv.x), f1 = bf2f(uv.y);
    float4 u0 = su[2 * k2], u1 = su[2 * k2 + 1];
    float4 v0 = sd[2 * k2], v1 = sd[2 * k2 + 1];
    s[0] += f0 * u0.x + f1 * u1.x; s[1] += f0 * u0.y + f1 * u1.y;
    s[2] += f0 * u0.z + f1 * u1.z; s[3] += f0 * u0.w + f1 * u1.w;
    d[0] += f0 * v0.x + f1 * v1.x; d[1] += f0 * v0.y + f1 * v1.y;
    d[2] += f0 * v0.z + f1 * v1.z; d[3] += f0 * v0.w + f1 * v1.w;
  }
#pragma unroll
  for (int h = 0; h < NH; ++h)
    for (int o = 32; o > 0; o >>= 1) {
      s[h] += __shfl_down(s[h], o);
      d[h] += __shfl_down(d[h], o);
    }
  if (lane == 0)
    for (int h = 0; h < NH; ++h) {
      as_[n * NH + h] = s[h];
      ad_[n * NH + h] = d[h];
    }
}

// ---------------------------------------------------------------------------
// Narrow per-head aggregation in the input domain (self-loop mean folded in)
// ---------------------------------------------------------------------------
template<int C>
__global__ __launch_bounds__(256) void aggn_kernel(const unsigned short* __restrict__ src,
                                                   const float* __restrict__ as_, const float* __restrict__ ad_,
                                                   const float* __restrict__ aee, const float* __restrict__ aesum,
                                                   const int* __restrict__ offs, const int* __restrict__ csr_src,
                                                   const int* __restrict__ csr_eid,
                                                   unsigned short* __restrict__ out) {
  constexpr int CPT = C / 256;
  const int n = blockIdx.x;
  const int tid = threadIdx.x;
  const int off = offs[n];
  const int deg = offs[n + 1] - off;
  __shared__ float minv[NH], dinv[NH], wself[NH];
  __shared__ float wch[32][NH];
  __shared__ int sch[32];
  if (tid < 64) {
    const int h = tid >> 4, slot = tid & 15;
    const float adn = ad_[n * NH + h];
    const float aself = lrelu(as_[n * NH + h] + adn + aesum[n * NH + h] / fmaxf((float)deg, 1.f));
    float m = (slot == 0) ? aself : -3.0e38f;
    for (int i = slot; i < deg; i += 16) {
      float a = lrelu(as_[csr_src[off + i] * NH + h] + adn + aee[csr_eid[off + i] * NH + h]);
      m = fmaxf(m, a);
    }
    for (int o = 1; o < 16; o <<= 1) m = fmaxf(m, __shfl_xor(m, o));
    float den = (slot == 0) ? __expf(aself - m) : 0.f;
    for (int i = slot; i < deg; i += 16) {
      float a = lrelu(as_[csr_src[off + i] * NH + h] + adn + aee[csr_eid[off + i] * NH + h]);
      den += __expf(a - m);
    }
    for (int o = 1; o < 16; o <<= 1) den += __shfl_xor(den, o);
    if (slot == 0) {
      minv[h] = m;
      dinv[h] = 1.0f / den;
      wself[h] = __expf(aself - m) / den;
    }
  }
  __syncthreads();
  float acc[NH][CPT];
#pragma unroll
  for (int h = 0; h < NH; ++h)
#pragma unroll
    for (int c = 0; c < CPT; ++c) acc[h][c] = 0.f;
  for (int base = 0; base < deg; base += 32) {
    const int cnt = min(32, deg - base);
    if (tid < cnt * NH) {
      const int i = tid >> 2, h = tid & 3;
      const int sidx = csr_src[off + base + i];
      float a = lrelu(as_[sidx * NH + h] + ad_[n * NH + h] + aee[csr_eid[off + base + i] * NH + h]);
      wch[i][h] = __expf(a - minv[h]) * dinv[h];
      if (h == 0) sch[i] = sidx;
    }
    __syncthreads();
    for (int i = 0; i < cnt; ++i) {
      const unsigned short* hp = src + (size_t)sch[i] * C + tid * CPT;
      float f[CPT];
      if constexpr (CPT == 2) {
        ushort2 u = *(const ushort2*)hp;
        f[0] = bf2f(u.x); f[1] = bf2f(u.y);
      } else {
        ushort4 u = *(const ushort4*)hp;
        f[0] = bf2f(u.x); f[1] = bf2f(u.y); f[2] = bf2f(u.z); f[3] = bf2f(u.w);
      }
#pragma unroll
      for (int h = 0; h < NH; ++h) {
        const float wv = wch[i][h];
#pragma unroll
        for (int c = 0; c < CPT; ++c) acc[h][c] += wv * f[c];
      }
    }
    __syncthreads();
  }
  {
    const unsigned short* hp = src + (size_t)n * C + tid * CPT;
    float f[CPT];
    if constexpr (CPT == 2) {
      ushort2 u = *(const ushort2*)hp;
      f[0] = bf2f(u.x); f[1] = bf2f(u.y);
    } else {
      ushort4 u = *(const ushort4*)hp;
      f[0] = bf2f(u.x); f[1] = bf2f(u.y); f[2] = bf2f(u.z); f[3] = bf2f(u.w);
    }
#pragma unroll
    for (int h = 0; h < NH; ++h) {
      const float wv = wself[h];
#pragma unroll
      for (int c = 0; c < CPT; ++c) acc[h][c] += wv * f[c];
    }
  }
#pragma unroll
  for (int h = 0; h < NH; ++h) {
    if constexpr (CPT == 2) {
      ushort2 o;
      o.x = f2bf(acc[h][0]); o.y = f2bf(acc[h][1]);
      *(ushort2*)&out[((size_t)n * NH + h) * C + tid * 2] = o;
    } else {
      ushort4 o;
      o.x = f2bf(acc[h][0]); o.y = f2bf(acc[h][1]); o.z = f2bf(acc[h][2]); o.w = f2bf(acc[h][3]);
      *(ushort4*)&out[((size_t)n * NH + h) * C + tid * 4] = o;
    }
  }
}

// ---------------------------------------------------------------------------
// bf16 MFMA GEMM, m97 structure + XCD swizzle. Tile 128 x BN (BN=128 or 64).
// C[M][N] = A[M][K] @ Bt[N][K]^T.  EPI: bias+prelu. WF: also write fp32.
// ---------------------------------------------------------------------------
template<int EPI, int WF, int BN>
__global__ __launch_bounds__(256) void mfma_gemm(const unsigned short* __restrict__ A,
                                                 const unsigned short* __restrict__ Bt,
                                                 unsigned short* __restrict__ C,
                                                 float* __restrict__ Cf,
                                                 int M, int N, int K,
                                                 const float* __restrict__ bias,
                                                 const float* __restrict__ pa) {
  constexpr int NFR = BN / 32;     // 16-col fragments per wave (4 or 2)
  __shared__ unsigned short As[128 * 32];
  __shared__ unsigned short Bs[BN * 32];
  // XCD-aware bijective swizzle (all grids here have nwg % 8 == 0)
  const int nwg = gridDim.x * gridDim.y;
  int id = blockIdx.y * gridDim.x + blockIdx.x;
  id = (id & 7) * (nwg >> 3) + (id >> 3);
  const int bx = id % gridDim.x, by = id / gridDim.x;
  const int tid = threadIdx.x;
  const int lane = tid & 63;
  const int w = tid >> 6;
  const int wr = w >> 1, wc = w & 1;
  const int brow = by * 128, bcol = bx * BN;
  const int r0 = tid >> 2;
  const int koff = (tid & 3) * 8;
  const int fr = lane & 15;
  const int fk = (lane >> 4) * 8;
  f32x4 acc[4][NFR] = {};
  for (int kt = 0; kt < K; kt += 32) {
    GLDS(A + (size_t)(brow + r0) * K + kt + koff, &As[tid * 8]);
    GLDS(A + (size_t)(brow + 64 + r0) * K + kt + koff, &As[2048 + tid * 8]);
    GLDS(Bt + (size_t)(bcol + r0) * K + kt + koff, &Bs[tid * 8]);
    if constexpr (BN == 128)
      GLDS(Bt + (size_t)(bcol + 64 + r0) * K + kt + koff, &Bs[2048 + tid * 8]);
    asm volatile("s_waitcnt vmcnt(0)" ::: "memory");
    __syncthreads();
    bf16x8 af[4], bfr[NFR];
#pragma unroll
    for (int mi = 0; mi < 4; ++mi)
      af[mi] = *(const bf16x8*)&As[(wr * 64 + mi * 16 + fr) * 32 + fk];
#pragma unroll
    for (int ni = 0; ni < NFR; ++ni)
      bfr[ni] = *(const bf16x8*)&Bs[(wc * (BN / 2) + ni * 16 + fr) * 32 + fk];
#pragma unroll
    for (int mi = 0; mi < 4; ++mi)
#pragma unroll
      for (int ni = 0; ni < NFR; ++ni)
        acc[mi][ni] = __builtin_amdgcn_mfma_f32_16x16x32_bf16(af[mi], bfr[ni], acc[mi][ni], 0, 0, 0);
    __syncthreads();
  }
  const float ap = EPI ? *pa : 0.f;
#pragma unroll
  for (int mi = 0; mi < 4; ++mi) {
    const int rb = brow + wr * 64 + mi * 16 + (lane >> 4) * 4;
#pragma unroll
    for (int ni = 0; ni < NFR; ++ni) {
      const int col = bcol + wc * (BN / 2) + ni * 16 + fr;
      float bv = 0.f;
      if (EPI) bv = bias[col];
#pragma unroll
      for (int r = 0; r < 4; ++r) {
        float v = acc[mi][ni][r];
        if (EPI) { v += bv; v = v >= 0.f ? v : ap * v; }
        C[(size_t)(rb + r) * N + col] = f2bf(v);
        if (WF) Cf[(size_t)(rb + r) * N + col] = v;
      }
    }
  }
}

// ---------------------------------------------------------------------------
// gate = gh2 @ gW3 + gb3 (bf16 matvec)
// ---------------------------------------------------------------------------
__global__ __launch_bounds__(256) void gate3_kernel(const unsigned short* __restrict__ gh2,
                                                    const float* __restrict__ gW3,
                                                    const float* __restrict__ gb3, float* __restrict__ gate) {
  const int n = blockIdx.x, tid = threadIdx.x;
  const unsigned short* row = gh2 + (size_t)n * HID;
  ushort4 u = *(const ushort4*)&row[tid * 4];
  float4 wv = *(const float4*)&gW3[tid * 4];
  float acc = bf2f(u.x) * wv.x + bf2f(u.y) * wv.y + bf2f(u.z) * wv.z + bf2f(u.w) * wv.w;
  for (int o = 32; o > 0; o >>= 1) acc += __shfl_down(acc, o);
  __shared__ float red[4];
  const int wid = tid >> 6, lane = tid & 63;
  if (lane == 0) red[wid] = acc;
  __syncthreads();
  if (tid == 0) gate[n] = red[0] + red[1] + red[2] + red[3] + gb3[0];
}

// ---------------------------------------------------------------------------
// Fused per-graph softmax + weighted pool (binary search on sorted batch)
// ---------------------------------------------------------------------------
__global__ __launch_bounds__(256) void pool2_kernel(const float* __restrict__ out2,
                                                    const float* __restrict__ gate,
                                                    const int* __restrict__ batch,
                                                    float* __restrict__ dout) {
  const int b = blockIdx.y;
  const int tid = threadIdx.x;
  const int col = blockIdx.x * 256 + tid;
  int lo = 0, hi = N_NODES;
  while (lo < hi) { int mid = (lo + hi) >> 1; if (batch[mid] < b) lo = mid + 1; else hi = mid; }
  const int s = lo;
  hi = N_NODES;
  while (lo < hi) { int mid = (lo + hi) >> 1; if (batch[mid] < b + 1) lo = mid + 1; else hi = mid; }
  const int e = lo;
  __shared__ float red[4];
  const int wid = tid >> 6, lane = tid & 63;
  float m = -3.0e38f;
  for (int n = s + tid; n < e; n += 256) m = fmaxf(m, gate[n]);
  for (int o = 32; o > 0; o >>= 1) m = fmaxf(m, __shfl_down(m, o));
  if (lane == 0) red[wid] = m;
  __syncthreads();
  m = fmaxf(fmaxf(red[0], red[1]), fmaxf(red[2], red[3]));
  __syncthreads();
  float sum = 0.f;
  for (int n = s + tid; n < e; n += 256) sum += __expf(gate[n] - m);
  for (int o = 32; o > 0; o >>= 1) sum += __shfl_down(sum, o);
  if (lane == 0) red[wid] = sum;
  __syncthreads();
  sum = red[0] + red[1] + red[2] + red[3];
  const float gi = 1.0f / fmaxf(sum, 1e-16f);
  float acc = 0.f;
  for (int n = s; n < e; ++n)
    acc += __expf(gate[n] - m) * gi * out2[(size_t)n * OUTD + col];
  dout[(size_t)b * OUTD + col] = acc;
}

// ---------------------------------------------------------------------------
// Workspace layout
// ---------------------------------------------------------------------------
#define MB(x) ((size_t)(x) * 1048576)
#define WS_XB     MB(0)     // 4 MB   bf16 x [4096][512]
#define WS_B1T    MB(4)     // 4 MB   bf16 stacked 0.25*W1^T [1024][2048]
#define WS_B2T    MB(8)     // 16 MB  bf16 stacked 0.25*W2^T [2048][4096]
#define WS_GW1T   MB(24)    // 4 MB   bf16 gW1^T [1024][2048]
#define WS_GW2T   MB(28)    // 2 MB   bf16 gW2^T [1024][1024]
#define WS_AGGX   MB(30)    // 16 MB  bf16 aggX [4096][2048]
#define WS_OUT1B  MB(46)    // 8 MB   bf16 out1 [4096][1024]
#define WS_AGGO   MB(54)    // 32 MB  bf16 aggO [4096][4096]
#define WS_OUT2F  MB(86)    // 32 MB  fp32 out2 [4096][2048]
#define WS_OUT2B  MB(118)   // 16 MB  bf16 out2
#define WS_GH1B   MB(134)   // 8 MB   bf16 gh1 [4096][1024]
#define WS_GH2B   MB(142)   // 8 MB   bf16 gh2
#define WS_SM     MB(150)
#define WS_AES1   (WS_SM + 0)        // 64 KB (zeroed)
#define WS_AES2   (WS_AES1 + 65536)  // 64 KB (zeroed)
#define WS_OFFS   (WS_AES2 + 65536)  // int[4097]
#define WS_CSRS   (WS_OFFS + 16640)
#define WS_CSRE   (WS_CSRS + 65536)
#define WS_AS1    (WS_CSRE + 65536)
#define WS_AD1    (WS_AS1 + 65536)
#define WS_AEE1   (WS_AD1 + 65536)
#define WS_AS2    (WS_AEE1 + 262144)
#define WS_AD2    (WS_AS2 + 65536)
#define WS_AEE2   (WS_AD2 + 65536)
#define WS_V1     (WS_AEE2 + 262144)
#define WS_V2     (WS_V1 + 8192)
#define WS_US1    (WS_V2 + 8192)
#define WS_UD1    (WS_US1 + 8192)
#define WS_US2    (WS_UD1 + 8192)
#define WS_UD2    (WS_US2 + 16384)
#define WS_GATE   (WS_UD2 + 16384)

extern "C" void kernel_launch(void* const* d_in, const int* in_sizes, int n_in,
                              void* d_out, int out_size, void* d_ws, size_t ws_size,
                              hipStream_t stream) {
  const float* x     = (const float*)d_in[0];
  const int*   ei    = (const int*)d_in[1];
  const float* ea    = (const float*)d_in[2];
  const int*   batch = (const int*)d_in[3];
  const float* W1    = (const float*)d_in[4];
  const float* asrc1 = (const float*)d_in[5];
  const float* adst1 = (const float*)d_in[6];
  const float* We1   = (const float*)d_in[7];
  const float* ae1w  = (const float*)d_in[8];
  const float* b1    = (const float*)d_in[9];
  const float* p1    = (const float*)d_in[10];
  const float* W2    = (const float*)d_in[11];
  const float* asrc2 = (const float*)d_in[12];
  const float* adst2 = (const float*)d_in[13];
  const float* We2   = (const float*)d_in[14];
  const float* ae2w  = (const float*)d_in[15];
  const float* b2    = (const float*)d_in[16];
  const float* p2    = (const float*)d_in[17];
  const float* gW1   = (const float*)d_in[18];
  const float* gb1   = (const float*)d_in[19];
  const float* gp1   = (const float*)d_in[20];
  const float* gW2   = (const float*)d_in[21];
  const float* gb2   = (const float*)d_in[22];
  const float* gp2   = (const float*)d_in[23];
  const float* gW3   = (const float*)d_in[24];
  const float* gb3   = (const float*)d_in[25];

  char* ws = (char*)d_ws;
  unsigned short* xb    = (unsigned short*)(ws + WS_XB);
  unsigned short* B1t   = (unsigned short*)(ws + WS_B1T);
  unsigned short* B2t   = (unsigned short*)(ws + WS_B2T);
  unsigned short* gW1t  = (unsigned short*)(ws + WS_GW1T);
  unsigned short* gW2t  = (unsigned short*)(ws + WS_GW2T);
  unsigned short* aggXb = (unsigned short*)(ws + WS_AGGX);
  unsigned short* out1b = (unsigned short*)(ws + WS_OUT1B);
  unsigned short* aggOb = (unsigned short*)(ws + WS_AGGO);
  float*          out2f = (float*)(ws + WS_OUT2F);
  unsigned short* out2b = (unsigned short*)(ws + WS_OUT2B);
  unsigned short* gh1b  = (unsigned short*)(ws + WS_GH1B);
  unsigned short* gh2b  = (unsigned short*)(ws + WS_GH2B);
  float* aesum1  = (float*)(ws + WS_AES1);
  float* aesum2  = (float*)(ws + WS_AES2);
  int*   offs    = (int*)(ws + WS_OFFS);
  int*   csr_src = (int*)(ws + WS_CSRS);
  int*   csr_eid = (int*)(ws + WS_CSRE);
  float* as1     = (float*)(ws + WS_AS1);
  float* ad1     = (float*)(ws + WS_AD1);
  float* aee1    = (float*)(ws + WS_AEE1);
  float* as2     = (float*)(ws + WS_AS2);
  float* ad2     = (float*)(ws + WS_AD2);
  float* aee2    = (float*)(ws + WS_AEE2);
  float* v1      = (float*)(ws + WS_V1);
  float* v2      = (float*)(ws + WS_V2);
  float* us1     = (float*)(ws + WS_US1);
  float* ud1     = (float*)(ws + WS_UD1);
  float* us2     = (float*)(ws + WS_US2);
  float* ud2     = (float*)(ws + WS_UD2);
  float* gate    = (float*)(ws + WS_GATE);
  float* dout    = (float*)d_out;

  hipMemsetAsync(ws + WS_AES1, 0, 131072, stream);

  // fused prep: weights, attention-vector folds, CSR, edge terms, x prep
  wprep_kernel<<<13312, dim3(32, 8), 0, stream>>>(W1, W2, gW1, gW2, B1t, B2t, gW1t, gW2t);
  vprep_kernel<<<2560, 256, 0, stream>>>(We1, ae1w, We2, ae2w, W1, asrc1, adst1, W2, asrc2, adst2,
                                         v1, v2, us1, ud1, us2, ud2);
  csr_kernel<<<1, 1024, 0, stream>>>(ei, offs, csr_src, csr_eid);
  ae_kernel<<<N_EDGES / 64, 256, 0, stream>>>(ea, ei, v1, v2, aee1, aee2, aesum1, aesum2);
  xprep_kernel<<<N_NODES / 4, 256, 0, stream>>>(x, us1, ud1, xb, as1, ad1);

  // layer 1: aggregate x, GEMM through stacked 0.25*W1
  aggn_kernel<CLIPD><<<N_NODES, 256, 0, stream>>>(xb, as1, ad1, aee1, aesum1, offs, csr_src, csr_eid, aggXb);
  mfma_gemm<1, 0, 64><<<dim3(HID / 64, N_NODES / 128), 256, 0, stream>>>(
      aggXb, B1t, out1b, nullptr, N_NODES, HID, NH * CLIPD, b1, p1);

  // layer 2: logits from out1, aggregate out1, GEMM through stacked 0.25*W2
  rowdot_o<<<N_NODES / 4, 256, 0, stream>>>(out1b, us2, ud2, as2, ad2);
  aggn_kernel<HID><<<N_NODES, 256, 0, stream>>>(out1b, as2, ad2, aee2, aesum2, offs, csr_src, csr_eid, aggOb);
  mfma_gemm<1, 1, 128><<<dim3(OUTD / 128, N_NODES / 128), 256, 0, stream>>>(
      aggOb, B2t, out2b, out2f, N_NODES, OUTD, NH * HID, b2, p2);

  // gate MLP
  mfma_gemm<1, 0, 64><<<dim3(HID / 64, N_NODES / 128), 256, 0, stream>>>(
      out2b, gW1t, gh1b, nullptr, N_NODES, HID, OUTD, gb1, gp1);
  mfma_gemm<1, 0, 64><<<dim3(HID / 64, N_NODES / 128), 256, 0, stream>>>(
      gh1b, gW2t, gh2b, nullptr, N_NODES, HID, HID, gb2, gp2);
  gate3_kernel<<<N_NODES, 256, 0, stream>>>(gh2b, gW3, gb3, gate);

  // fused attentional pooling
  pool2_kernel<<<dim3(OUTD / 256, NB), 256, 0, stream>>>(out2f, gate, batch, dout);
}